// Round 9
// baseline (745.487 us; speedup 1.0000x reference)
//
#include <hip/hip_runtime.h>
#include <math.h>

constexpr int Bn = 4;
constexpr int S  = 64;
constexpr int N  = 4096;  // S*S

#define DEV static __device__ __forceinline__

typedef __attribute__((ext_vector_type(8))) short bf16x8;
typedef __attribute__((ext_vector_type(4))) float f32x4;

DEV unsigned short bfc(float x) {  // f32 -> bf16 RNE
  unsigned u = __float_as_uint(x);
  unsigned r = (u + 0x7FFFu + ((u >> 16) & 1u)) >> 16;
  return (unsigned short)r;
}

DEV void fma4(float4& a, float s, const float4 u) {
  a.x = fmaf(s, u.x, a.x); a.y = fmaf(s, u.y, a.y);
  a.z = fmaf(s, u.z, a.z); a.w = fmaf(s, u.w, a.w);
}

// async global->LDS, 16B per lane; lds base must be wave-uniform (lane i lands at +i*16)
DEV void gload_lds16(const unsigned short* g, unsigned short* l) {
  __builtin_amdgcn_global_load_lds(
      (const __attribute__((address_space(1))) void*)g,
      (__attribute__((address_space(3))) void*)l, 16, 0, 0);
}

// pack two f32 -> one u32 of 2 bf16 (low = lo), HW RNE (matches bfc for normals)
DEV unsigned cvtpk_bf16(float lo, float hi) {
  unsigned r;
  asm("v_cvt_pk_bf16_f32 %0, %1, %2" : "=v"(r) : "v"(lo), "v"(hi));
  return r;
}
// a.hi32lanes <-> b.lo32lanes :  a' = [a.q0,a.q1,b.q0,b.q1], b' = [a.q2,a.q3,b.q2,b.q3]
DEV void pswap32(unsigned& a, unsigned& b) {
  asm("v_permlane32_swap_b32 %0, %1" : "+v"(a), "+v"(b));
}
// odd 16-rows of a <-> even 16-rows of b : a' = [a.r0,b.r0,a.r2,b.r2], b' = [a.r1,b.r1,a.r3,b.r3]
DEV void pswap16(unsigned& a, unsigned& b) {
  asm("v_permlane16_swap_b32 %0, %1" : "+v"(a), "+v"(b));
}

// ---------------- all weight transposes in ONE launch (range-decoded) ----------------
__global__ __launch_bounds__(256) void wtr_all_kernel(
    const float* __restrict__ w1, const float* __restrict__ w2,
    const float* __restrict__ a0, const float* __restrict__ a1,
    const float* __restrict__ a2, const float* __restrict__ a3,
    unsigned short* __restrict__ wt1, unsigned short* __restrict__ wt2,
    unsigned short* __restrict__ wtbr) {
  const int blk = blockIdx.x;  // 5248 total
  const float* src; unsigned short* dst; int Cin, Cout, T, base;
  if (blk < 1152)      { src = w1; dst = wt1; Cout = 256; Cin = 128; T = 9; base = 0; }
  else if (blk < 3456) { src = w2; dst = wt2; Cout = 256; Cin = 256; T = 9; base = 1152; }
  else if (blk < 3520) { src = a0; dst = wtbr + (size_t)4 * 64 * 256;
                         Cout = 64; Cin = 256; T = 1; base = 3456; }
  else if (blk < 4096) { src = a1; dst = wtbr + (size_t)1 * 9 * 64 * 256;
                         Cout = 64; Cin = 256; T = 9; base = 3520; }
  else if (blk < 4672) { src = a2; dst = wtbr + (size_t)2 * 9 * 64 * 256;
                         Cout = 64; Cin = 256; T = 9; base = 4096; }
  else                 { src = a3; dst = wtbr + (size_t)3 * 9 * 64 * 256;
                         Cout = 64; Cin = 256; T = 9; base = 4672; }
  int i = (blk - base) * 256 + threadIdx.x;
  int ci = i % Cin;
  int r  = i / Cin;
  int t  = r / Cout;
  int co = r - t * Cout;
  dst[i] = bfc(src[((size_t)co * Cin + ci) * T + t]);
}

// ---------------- maxpool 2x2 -> NHWC bf16 padded (halo=1) ----------------
__global__ __launch_bounds__(256) void pool_kernel(const float* __restrict__ x,
                                                   unsigned short* __restrict__ Pp1) {
  int i = blockIdx.x * 256 + threadIdx.x;  // 524288
  int xg = i & 15, y = (i >> 4) & 63, c = (i >> 10) & 127, b = i >> 17;
  const float* s = x + (((size_t)(b * 128 + c) * 128) + 2 * y) * 128 + 8 * xg;
  float4 u0 = *(const float4*)(s), u1 = *(const float4*)(s + 4);
  float4 u2 = *(const float4*)(s + 128), u3 = *(const float4*)(s + 132);
  float m0 = fmaxf(fmaxf(u0.x, u0.y), fmaxf(u2.x, u2.y));
  float m1 = fmaxf(fmaxf(u0.z, u0.w), fmaxf(u2.z, u2.w));
  float m2 = fmaxf(fmaxf(u1.x, u1.y), fmaxf(u3.x, u3.y));
  float m3 = fmaxf(fmaxf(u1.z, u1.w), fmaxf(u3.z, u3.w));
  unsigned short* d = Pp1 + (((size_t)b * 66 + y + 1) * 66 + xg * 4 + 1) * 128 + c;
  d[0] = bfc(m0); d[128] = bfc(m1); d[256] = bfc(m2); d[384] = bfc(m3);
}

// ---------------- dc conv: implicit GEMM, co-tile 64 at FULL depth, 8 waves --------
// r8's co-split halved B-reuse (input shared by 2 co-frags) -> +453 MB input reads
// (+39 us, measured). This keeps r8's single full-depth output buffer (t1 traffic
// halved vs r7's ci-split) but restores a[4]-amortization: 512-thread blocks,
// wave w owns 16 n-cols, acc[4] co-frags share ONE B-load. B-load instr count
// identical to r7; weights re-read 8x/block through L1 (4 KB slabs, cheap).
// Grid 512 blocks x 8 waves = 16 waves/CU (same occupancy as r7).
// Accumulation order identical to r8's validated full-depth loop -> bit-exact.
template <int CTOT>
__global__ __launch_bounds__(512) void dcconv_kernel(
    const unsigned short* __restrict__ in, const unsigned short* __restrict__ wt,
    float* __restrict__ out) {
  const int Wp = 66;
  const int w = threadIdx.x >> 6, lane = threadIdx.x & 63;
  const int ln = lane & 15, quad = lane >> 4;
  const int b = blockIdx.z, co0 = blockIdx.y * 64;
  const int n0 = blockIdx.x * 128 + w * 16;
  const unsigned short* inb = in + (size_t)b * Wp * Wp * CTOT;
  size_t pix;
  {
    int n = n0 + ln;
    int y = n >> 6, x = n & 63;
    pix = ((size_t)y * Wp + x) * CTOT;
  }
  f32x4 acc[4];
#pragma unroll
  for (int i = 0; i < 4; i++) acc[i] = (f32x4)(0.f);
#pragma unroll
  for (int ky = 0; ky < 3; ky++)
#pragma unroll
    for (int kx = 0; kx < 3; kx++) {
      const size_t toff = ((size_t)ky * Wp + kx) * CTOT;
      const unsigned short* wtap = wt + (size_t)(ky * 3 + kx) * 256 * CTOT;
      for (int kc = 0; kc < CTOT / 32; kc++) {
        const int ko = kc * 32 + quad * 8;
        bf16x8 a[4];
#pragma unroll
        for (int i = 0; i < 4; i++)
          a[i] = *(const bf16x8*)(wtap + (size_t)(co0 + i * 16 + ln) * CTOT + ko);
        bf16x8 bb = *(const bf16x8*)(inb + pix + toff + ko);
#pragma unroll
        for (int i = 0; i < 4; i++)
          acc[i] = __builtin_amdgcn_mfma_f32_16x16x32_bf16(a[i], bb, acc[i], 0, 0, 0);
      }
    }
#pragma unroll
  for (int i = 0; i < 4; i++)
#pragma unroll
    for (int r = 0; r < 4; r++)
      out[((size_t)(b * 256 + co0 + i * 16 + quad * 4 + r)) * N + n0 + ln] = acc[i][r];
}

// ---------------- all 4 ASPP branches, implicit GEMM on Pp3 (halo=9) ----------------
__global__ __launch_bounds__(256) void branch_kernel(
    const unsigned short* __restrict__ in, const unsigned short* __restrict__ wtall,
    float* __restrict__ br) {
  const int Wp = 82, halo = 9, CIN = 256;
  const int w = threadIdx.x >> 6, lane = threadIdx.x & 63;
  const int ln = lane & 15, quad = lane >> 4;
  const int bb = blockIdx.y;
  const int kbr = bb >> 2, b = bb & 3;
  const int dil = (kbr == 0) ? 1 : 3 * kbr;
  const int klo = (kbr == 0) ? 1 : 0, khi = (kbr == 0) ? 2 : 3;
  const int hd = halo - dil;
  const int cw = (w & 1) * 32, nw = (w >> 1) * 32;
  const int n0 = blockIdx.x * 64 + nw;
  const unsigned short* inb = in + (size_t)b * Wp * Wp * CIN;
  size_t pix[2];
#pragma unroll
  for (int j = 0; j < 2; j++) {
    int n = n0 + j * 16 + ln;
    int y = n >> 6, x = n & 63;
    pix[j] = ((size_t)(y + hd) * Wp + x + hd) * CIN;
  }
  f32x4 acc[2][2];
#pragma unroll
  for (int i = 0; i < 2; i++)
#pragma unroll
    for (int j = 0; j < 2; j++) acc[i][j] = (f32x4)(0.f);
  for (int ky = klo; ky < khi; ky++)
    for (int kx = klo; kx < khi; kx++) {
      const size_t toff = ((size_t)ky * Wp + kx) * dil * CIN;
      const unsigned short* wtap =
          wtall + ((size_t)kbr * 9 + ky * 3 + kx) * 64 * CIN;
      for (int kc = 0; kc < CIN / 32; kc++) {
        const int ko = kc * 32 + quad * 8;
        bf16x8 a[2], bv[2];
#pragma unroll
        for (int i = 0; i < 2; i++)
          a[i] = *(const bf16x8*)(wtap + (size_t)(cw + i * 16 + ln) * CIN + ko);
#pragma unroll
        for (int j = 0; j < 2; j++)
          bv[j] = *(const bf16x8*)(inb + pix[j] + toff + ko);
#pragma unroll
        for (int i = 0; i < 2; i++)
#pragma unroll
          for (int j = 0; j < 2; j++)
            acc[i][j] = __builtin_amdgcn_mfma_f32_16x16x32_bf16(a[i], bv[j], acc[i][j], 0, 0, 0);
      }
    }
#pragma unroll
  for (int i = 0; i < 2; i++)
#pragma unroll
    for (int j = 0; j < 2; j++)
#pragma unroll
      for (int r = 0; r < 4; r++)
        br[((size_t)bb * 64 + cw + i * 16 + quad * 4 + r) * N + n0 + j * 16 + ln] =
            acc[i][j][r];
}

// ---------------- BN stats, all 4 ASPP branches in one launch (float4 loads) --------
__global__ __launch_bounds__(256) void bn_stats_all_kernel(
    const float* __restrict__ br,
    const float* __restrict__ g0, const float* __restrict__ b0,
    const float* __restrict__ g1, const float* __restrict__ b1,
    const float* __restrict__ g2, const float* __restrict__ b2,
    const float* __restrict__ g3, const float* __restrict__ b3,
    float* __restrict__ sta) {
  const int kbr = blockIdx.x >> 6, c = blockIdx.x & 63;
  const float* gamma = kbr == 0 ? g0 : (kbr == 1 ? g1 : (kbr == 2 ? g2 : g3));
  const float* beta  = kbr == 0 ? b0 : (kbr == 1 ? b1 : (kbr == 2 ? b2 : b3));
  const float* t = br + (size_t)kbr * 1048576;
  float* ss = sta + kbr * 128;
  float s = 0.f, s2 = 0.f;
  for (int b = 0; b < Bn; b++) {
    const float* p = t + ((size_t)(b * 64 + c)) * N;
    for (int i = threadIdx.x; i < N / 4; i += 256) {
      float4 v = *(const float4*)(p + (size_t)i * 4);
      s += (v.x + v.y) + (v.z + v.w);
      s2 = fmaf(v.x, v.x, s2); s2 = fmaf(v.y, v.y, s2);
      s2 = fmaf(v.z, v.z, s2); s2 = fmaf(v.w, v.w, s2);
    }
  }
  for (int off = 32; off; off >>= 1) {
    s += __shfl_down(s, off, 64);
    s2 += __shfl_down(s2, off, 64);
  }
  __shared__ float rs[4], rs2[4];
  const int wid = threadIdx.x >> 6, lane = threadIdx.x & 63;
  if (lane == 0) { rs[wid] = s; rs2[wid] = s2; }
  __syncthreads();
  if (threadIdx.x == 0) {
    float S1 = rs[0] + rs[1] + rs[2] + rs[3];
    float S2 = rs2[0] + rs2[1] + rs2[2] + rs2[3];
    const float cnt = (float)(Bn * N);
    float mean = S1 / cnt;
    float var = S2 / cnt - mean * mean;
    float sc = gamma[c] * rsqrtf(var + 1e-5f);
    ss[2 * c] = sc;
    ss[2 * c + 1] = beta[c] - mean * sc;
  }
}

// ---------------- BN stats, dc conv output (single fp32 buffer, C=256) --------------
__global__ __launch_bounds__(256) void bn_stats_dc_kernel(
    const float* __restrict__ t, const float* __restrict__ gamma,
    const float* __restrict__ beta, float* __restrict__ ss) {
  const int c = blockIdx.x;  // 256
  float s = 0.f, s2 = 0.f;
  for (int b = 0; b < Bn; b++) {
    const float* p = t + ((size_t)(b * 256 + c)) * N;
    for (int i = threadIdx.x; i < N / 4; i += 256) {
      float4 v = *(const float4*)(p + (size_t)i * 4);
      s += (v.x + v.y) + (v.z + v.w);
      s2 = fmaf(v.x, v.x, s2); s2 = fmaf(v.y, v.y, s2);
      s2 = fmaf(v.z, v.z, s2); s2 = fmaf(v.w, v.w, s2);
    }
  }
  for (int off = 32; off; off >>= 1) {
    s += __shfl_down(s, off, 64);
    s2 += __shfl_down(s2, off, 64);
  }
  __shared__ float rs[4], rs2[4];
  const int wid = threadIdx.x >> 6, lane = threadIdx.x & 63;
  if (lane == 0) { rs[wid] = s; rs2[wid] = s2; }
  __syncthreads();
  if (threadIdx.x == 0) {
    float S1 = rs[0] + rs[1] + rs[2] + rs[3];
    float S2 = rs2[0] + rs2[1] + rs2[2] + rs2[3];
    const float cnt = (float)(Bn * N);
    float mean = S1 / cnt;
    float var = S2 / cnt - mean * mean;
    float sc = gamma[c] * rsqrtf(var + 1e-5f);
    ss[2 * c] = sc;
    ss[2 * c + 1] = beta[c] - mean * sc;
  }
}

// ---------------- BN+ReLU (single src) -> NHWC bf16 padded ----------------
__global__ __launch_bounds__(256) void bn_norm_pad_kernel(
    const float* __restrict__ ta, const float* __restrict__ ss,
    unsigned short* __restrict__ outp, int Wp, int halo) {
  int i = blockIdx.x * 256 + threadIdx.x;
  int n = i & 4095, cg = (i >> 12) & 63, b = i >> 18;
  int c0 = cg * 4;
  ushort4 pk;
  float v0, v1, v2, v3;
  {
    size_t i0 = ((size_t)(b * 256 + c0 + 0)) * N + n;
    size_t i1 = i0 + N, i2 = i1 + N, i3 = i2 + N;
    v0 = fmaxf(fmaf(ta[i0], ss[2 * (c0 + 0)], ss[2 * (c0 + 0) + 1]), 0.f);
    v1 = fmaxf(fmaf(ta[i1], ss[2 * (c0 + 1)], ss[2 * (c0 + 1) + 1]), 0.f);
    v2 = fmaxf(fmaf(ta[i2], ss[2 * (c0 + 2)], ss[2 * (c0 + 2) + 1]), 0.f);
    v3 = fmaxf(fmaf(ta[i3], ss[2 * (c0 + 3)], ss[2 * (c0 + 3) + 1]), 0.f);
  }
  pk.x = bfc(v0); pk.y = bfc(v1); pk.z = bfc(v2); pk.w = bfc(v3);
  int y = n >> 6, x = n & 63;
  *(ushort4*)(outp + (((size_t)b * Wp + y + halo) * Wp + x + halo) * 256 + c0) = pk;
}

// ---------------- q/k/v 1x1 convs FUSED (one br read for all 3 projections) ----------
__global__ __launch_bounds__(256) void qkv_kernel(
    const float* __restrict__ br, const float* __restrict__ sta,
    const float* __restrict__ wq, const float* __restrict__ bq,
    const float* __restrict__ wk, const float* __restrict__ bk,
    const float* __restrict__ wv, const float* __restrict__ bvb,
    unsigned short* __restrict__ qTo, unsigned short* __restrict__ kTo,
    unsigned short* __restrict__ vbo) {
  const int bb = blockIdx.z, dg = blockIdx.y;
  __shared__ float wl[3][64 * 16];
  __shared__ float ssl[128];
  const int d0b = dg * 16;
  if (threadIdx.x < 128) ssl[threadIdx.x] = sta[(bb >> 2) * 128 + threadIdx.x];
  for (int i = threadIdx.x; i < 64 * 16; i += 256) {
    const size_t widx = (size_t)(d0b + (i & 15)) * 64 + (i >> 4);
    wl[0][i] = wq[widx];
    wl[1][i] = wk[widx];
    wl[2][i] = wv[widx];
  }
  __syncthreads();
  const int tn = threadIdx.x & 63, td = threadIdx.x >> 6;
  const int n0 = blockIdx.x * 256 + tn * 4;
  const int d0 = d0b + td * 4;
  const float* inb = br + (size_t)bb * 64 * N;
  float4 acc[3][4];
#pragma unroll
  for (int j = 0; j < 4; j++) {
    float bq_ = bq[d0 + j], bk_ = bk[d0 + j], bv_ = bvb[d0 + j];
    acc[0][j] = make_float4(bq_, bq_, bq_, bq_);
    acc[1][j] = make_float4(bk_, bk_, bk_, bk_);
    acc[2][j] = make_float4(bv_, bv_, bv_, bv_);
  }
  for (int ci = 0; ci < 64; ci++) {
    float4 u = *(const float4*)(inb + (size_t)ci * N + n0);
    const float sc = ssl[2 * ci], of = ssl[2 * ci + 1];
    u.x = fmaxf(fmaf(u.x, sc, of), 0.f);
    u.y = fmaxf(fmaf(u.y, sc, of), 0.f);
    u.z = fmaxf(fmaf(u.z, sc, of), 0.f);
    u.w = fmaxf(fmaf(u.w, sc, of), 0.f);
#pragma unroll
    for (int p = 0; p < 3; p++) {
      float4 wv4 = *(const float4*)(&wl[p][ci * 16 + td * 4]);
      fma4(acc[p][0], wv4.x, u); fma4(acc[p][1], wv4.y, u);
      fma4(acc[p][2], wv4.z, u); fma4(acc[p][3], wv4.w, u);
    }
  }
  const size_t slab = (size_t)bb * N * 64;
  // q, k: transposed [n][d] bf16
#pragma unroll
  for (int p = 0; p < 2; p++) {
    unsigned short* o = (p == 0 ? qTo : kTo) + slab;
#pragma unroll
    for (int nn = 0; nn < 4; nn++) {
      ushort4 pk;
      pk.x = bfc(((const float*)&acc[p][0])[nn]);
      pk.y = bfc(((const float*)&acc[p][1])[nn]);
      pk.z = bfc(((const float*)&acc[p][2])[nn]);
      pk.w = bfc(((const float*)&acc[p][3])[nn]);
      *(ushort4*)(o + (size_t)(n0 + nn) * 64 + d0) = pk;
    }
  }
  // v: [d][n] bf16
  {
    unsigned short* o = vbo + slab;
#pragma unroll
    for (int j = 0; j < 4; j++) {
      ushort4 pk;
      pk.x = bfc(acc[2][j].x); pk.y = bfc(acc[2][j].y);
      pk.z = bfc(acc[2][j].z); pk.w = bfc(acc[2][j].w);
      *(ushort4*)(o + (size_t)(d0 + j) * N + n0) = pk;
    }
  }
}

// ---------------- posT[n][d] = rel_w[d][h] + rel_h[d][w], bf16 ----------------
__global__ __launch_bounds__(256) void posT_kernel(
    const float* __restrict__ rel_h, const float* __restrict__ rel_w,
    unsigned short* __restrict__ posT) {
  int i = blockIdx.x * 256 + threadIdx.x;  // 65536
  int n = i >> 4, dq = (i & 15) * 4;
  int h = n >> 6, wc = n & 63;
  ushort4 pk;
  pk.x = bfc(rel_w[(dq + 0) * 64 + h] + rel_h[(dq + 0) * 64 + wc]);
  pk.y = bfc(rel_w[(dq + 1) * 64 + h] + rel_h[(dq + 1) * 64 + wc]);
  pk.z = bfc(rel_w[(dq + 2) * 64 + h] + rel_h[(dq + 2) * 64 + wc]);
  pk.w = bfc(rel_w[(dq + 3) * 64 + h] + rel_h[(dq + 3) * 64 + wc]);
  *(ushort4*)(posT + (size_t)n * 64 + dq) = pk;
}

// ---------------- flash v7: XCD-pinned slabs; V hoisted over softmax ----------------
// (unchanged since round 5)
__global__ __launch_bounds__(256, 3) void flash3_kernel(
    const unsigned short* __restrict__ qT, const unsigned short* __restrict__ kT,
    const unsigned short* __restrict__ posT, const unsigned short* __restrict__ vb,
    float* __restrict__ o_part, float* __restrict__ ml) {
  const int lin = blockIdx.x;
  const int xcd = lin & 7, slot = lin >> 3;
  const int bb = xcd * 2 + (slot & 1);
  const int rest = slot >> 1;
  const int mtile = rest & 31, split = rest >> 5;
  const size_t slab = (size_t)bb * N * 64;
  const unsigned short* qTs = qT + slab;
  const unsigned short* kTs = kT + slab;
  const unsigned short* vbs = vb + slab;
  const int w = threadIdx.x >> 6, lane = threadIdx.x & 63;
  const int ln = lane & 15, quad = lane >> 4;
  const int m0 = mtile * 128 + w * 32;  // wave's 32 m-rows (2 frags)
  // As[buf][chunk s][c-row 64][32 halfs]; chunk s: s<2 -> kT halfs (s&1)*32, s>=2 -> qT
  __shared__ __align__(16) unsigned short As[2][4][64][32];   // 32 KB

  // wave w stages chunk w (4 instrs of 1 KB covering rows j*16..j*16+15).
  // Lane i lands at LDS row i>>2, phys 16B-chunk i&3; fetch the logical chunk
  // (i&3)^((i>>3)&3) so the read-side XOR recovers linear data.
  const unsigned short* ssrc = (w < 2) ? kTs : qTs;
  const int rsub = lane >> 2;
  const int csw  = (lane & 3) ^ ((lane >> 3) & 3);
  const int ksub = (w & 1) * 32 + csw * 8;
  auto stage = [&](int c0, int bufi) {
#pragma unroll
    for (int j = 0; j < 4; j++)
      gload_lds16(ssrc + (size_t)(c0 + j * 16 + rsub) * 64 + ksub,
                  &As[bufi][w][j * 16][0]);
  };

  // m-side B fragments: s<2 -> q rows, s>=2 -> pos rows (loaded once)
  bf16x8 bq[4][2];
#pragma unroll
  for (int s = 0; s < 4; s++) {
    const unsigned short* src = (s < 2) ? qTs : posT;
#pragma unroll
    for (int mf = 0; mf < 2; mf++)
      bq[s][mf] = *(const bf16x8*)(src + (size_t)(m0 + mf * 16 + ln) * 64 +
                                   (s & 1) * 32 + quad * 8);
  }

  float m_run[2] = {-3.0e38f, -3.0e38f}, l_run[2] = {0.f, 0.f};
  f32x4 o_acc[4][2];
#pragma unroll
  for (int dt = 0; dt < 4; dt++)
#pragma unroll
    for (int mf = 0; mf < 2; mf++) o_acc[dt][mf] = (f32x4)(0.f);

  const int qsw = (quad ^ ((ln >> 1) & 3)) * 8;  // swizzled read col (halfs)
  const int cbeg = split * 1024;
  stage(cbeg, 0);
  for (int t = 0; t < 16; t++) {
    const int c0 = cbeg + t * 64;
    const int buf = t & 1;
    __syncthreads();               // staging(t) complete; buf (t+1)&1 free
    if (t < 15) stage(c0 + 64, buf ^ 1);  // overlaps compute below
    // ---- S^T from LDS: st[jt][mf][r] = St[c0+jt*16+quad*4+r][m0+mf*16+ln]
    f32x4 st[4][2];
#pragma unroll
    for (int jt = 0; jt < 4; jt++)
#pragma unroll
      for (int mf = 0; mf < 2; mf++) st[jt][mf] = (f32x4)(0.f);
    __builtin_amdgcn_s_setprio(1);
#pragma unroll
    for (int s = 0; s < 4; s++) {
#pragma unroll
      for (int jt = 0; jt < 4; jt++) {
        bf16x8 a = *(const bf16x8*)(&As[buf][s][jt * 16 + ln][qsw]);
#pragma unroll
        for (int mf = 0; mf < 2; mf++)
          st[jt][mf] = __builtin_amdgcn_mfma_f32_16x16x32_bf16(a, bq[s][mf], st[jt][mf], 0, 0, 0);
      }
    }
    __builtin_amdgcn_s_setprio(0);
    // ---- V loads issued EARLY (independent of softmax; latency hides under it)
    bf16x8 av[2][4];
#pragma unroll
    for (int tt = 0; tt < 2; tt++)
#pragma unroll
      for (int dt = 0; dt < 4; dt++)
        av[tt][dt] = *(const bf16x8*)(vbs + (size_t)(dt * 16 + ln) * N + c0 + tt * 32 + quad * 8);
    // ---- online softmax per mf (row state scalar per lane); P stays in regs
    unsigned P0[2][4], P1[2][4];  // [mf][jt]: packed bf16 pairs (c offsets 0,1 / 2,3)
#pragma unroll
    for (int mf = 0; mf < 2; mf++) {
      float mj[4];
#pragma unroll
      for (int jt = 0; jt < 4; jt++)
        mj[jt] = fmaxf(fmaxf(st[jt][mf][0], st[jt][mf][1]),
                       fmaxf(st[jt][mf][2], st[jt][mf][3]));
      float mx = fmaxf(fmaxf(mj[0], mj[1]), fmaxf(mj[2], mj[3]));
      mx = fmaxf(mx, __shfl_xor(mx, 16, 64));
      mx = fmaxf(mx, __shfl_xor(mx, 32, 64));
      // exact skip: if no lane grew, alpha==1.0 for every lane -> rescale is
      // a bit-exact identity and can be skipped entirely.
      if (!__all(mx <= m_run[mf])) {
        const float m_new = fmaxf(m_run[mf], mx);
        const float alpha = __expf(m_run[mf] - m_new);
        l_run[mf] *= alpha;
#pragma unroll
        for (int dt = 0; dt < 4; dt++)
#pragma unroll
          for (int r = 0; r < 4; r++) o_acc[dt][mf][r] *= alpha;
        m_run[mf] = m_new;
      }
      const float mc = m_run[mf];
      float psum = 0.f;
#pragma unroll
      for (int jt = 0; jt < 4; jt++) {
        float e0 = __expf(st[jt][mf][0] - mc);
        float e1 = __expf(st[jt][mf][1] - mc);
        float e2 = __expf(st[jt][mf][2] - mc);
        float e3 = __expf(st[jt][mf][3] - mc);
        psum += (e0 + e1) + (e2 + e3);
        P0[mf][jt] = cvtpk_bf16(e0, e1);
        P1[mf][jt] = cvtpk_bf16(e2, e3);
      }
      psum += __shfl_xor(psum, 16, 64);
      psum += __shfl_xor(psum, 32, 64);
      l_run[mf] += psum;
    }
    // ---- PV: O[d][m] += V[d][c] * P[c][m]
    // B-frag for (tt, quad q): c = tt*32 + q*8 + j, j=0..7, col m=ln.
    // permlane32(X,Y) -> [x0,x1,y0,y1],[x2,x3,y2,y3]; permlane16 -> [x0,x2,y0,y2],[x1,x3,y1,y3]
    __builtin_amdgcn_s_setprio(1);
#pragma unroll
    for (int tt = 0; tt < 2; tt++) {
#pragma unroll
      for (int mf = 0; mf < 2; mf++) {
        unsigned x0 = P0[mf][2 * tt], y0 = P0[mf][2 * tt + 1];
        pswap32(x0, y0); pswap16(x0, y0);   // x0 = word0, y0 = word2
        unsigned x1 = P1[mf][2 * tt], y1 = P1[mf][2 * tt + 1];
        pswap32(x1, y1); pswap16(x1, y1);   // x1 = word1, y1 = word3
        union { unsigned u[4]; bf16x8 v; } bp;
        bp.u[0] = x0; bp.u[1] = x1; bp.u[2] = y0; bp.u[3] = y1;
#pragma unroll
        for (int dt = 0; dt < 4; dt++)
          o_acc[dt][mf] = __builtin_amdgcn_mfma_f32_16x16x32_bf16(av[tt][dt], bp.v, o_acc[dt][mf], 0, 0, 0);
      }
    }
    __builtin_amdgcn_s_setprio(0);
  }
  // ---- epilogue: unnormalized partials
  float* ob = o_part + ((size_t)(split * 16 + bb) * 64) * N;
#pragma unroll
  for (int dt = 0; dt < 4; dt++)
#pragma unroll
    for (int mf = 0; mf < 2; mf++)
#pragma unroll
      for (int r = 0; r < 4; r++) {
        int d = dt * 16 + quad * 4 + r;
        ob[(size_t)d * N + m0 + mf * 16 + ln] = o_acc[dt][mf][r];
      }
  if (quad == 0) {
#pragma unroll
    for (int mf = 0; mf < 2; mf++) {
      int m = m0 + mf * 16 + ln;
      ml[((size_t)(split * 16 + bb) * 2 + 0) * N + m] = m_run[mf];
      ml[((size_t)(split * 16 + bb) * 2 + 1) * N + m] = l_run[mf];
    }
  }
}

// ---------------- combine partials -> d_out (weights computed inline) ---------------
__global__ __launch_bounds__(256) void comb_kernel(const float* __restrict__ o_part,
                                                   const float* __restrict__ ml,
                                                   float* __restrict__ out) {
  int i = blockIdx.x * 256 + threadIdx.x;
  int m4 = i & 1023, d = (i >> 10) & 63, bb = i >> 16;
  int kbr = bb >> 2, b = bb & 3;
  float mvv[4][4], lvv[4][4];
#pragma unroll
  for (int s = 0; s < 4; s++) {
    float4 t0 = *(const float4*)(ml + ((size_t)(s * 16 + bb) * 2 + 0) * N + m4 * 4);
    float4 t1 = *(const float4*)(ml + ((size_t)(s * 16 + bb) * 2 + 1) * N + m4 * 4);
    mvv[s][0] = t0.x; mvv[s][1] = t0.y; mvv[s][2] = t0.z; mvv[s][3] = t0.w;
    lvv[s][0] = t1.x; lvv[s][1] = t1.y; lvv[s][2] = t1.z; lvv[s][3] = t1.w;
  }
  float w4[4][4];
#pragma unroll
  for (int mm = 0; mm < 4; mm++) {
    float M = fmaxf(fmaxf(mvv[0][mm], mvv[1][mm]), fmaxf(mvv[2][mm], mvv[3][mm]));
    float wsc[4], denom = 0.f;
#pragma unroll
    for (int s = 0; s < 4; s++) {
      wsc[s] = __expf(mvv[s][mm] - M);
      denom = fmaf(wsc[s], lvv[s][mm], denom);
    }
    float inv = 1.0f / denom;
#pragma unroll
    for (int s = 0; s < 4; s++) w4[s][mm] = wsc[s] * inv;
  }
  float4 acc = make_float4(0.f, 0.f, 0.f, 0.f);
#pragma unroll
  for (int s = 0; s < 4; s++) {
    const float4 o = *(const float4*)(o_part + ((size_t)(s * 16 + bb) * 64 + d) * N + m4 * 4);
    acc.x = fmaf(o.x, w4[s][0], acc.x); acc.y = fmaf(o.y, w4[s][1], acc.y);
    acc.z = fmaf(o.z, w4[s][2], acc.z); acc.w = fmaf(o.w, w4[s][3], acc.w);
  }
  *(float4*)(out + ((size_t)(b * 256 + kbr * 64 + d)) * N + m4 * 4) = acc;
}

extern "C" void kernel_launch(void* const* d_in, const int* in_sizes, int n_in,
                              void* d_out, int out_size, void* d_ws, size_t ws_size,
                              hipStream_t stream) {
  const float* x      = (const float*)d_in[0];
  const float* dc_w1  = (const float*)d_in[1];
  const float* dc_g1  = (const float*)d_in[3];
  const float* dc_be1 = (const float*)d_in[4];
  const float* dc_w2  = (const float*)d_in[5];
  const float* dc_g2  = (const float*)d_in[7];
  const float* dc_be2 = (const float*)d_in[8];
  const float* aspp_w[4] = {(const float*)d_in[9],  (const float*)d_in[12],
                            (const float*)d_in[15], (const float*)d_in[18]};
  const float* aspp_g[4] = {(const float*)d_in[10], (const float*)d_in[13],
                            (const float*)d_in[16], (const float*)d_in[19]};
  const float* aspp_b[4] = {(const float*)d_in[11], (const float*)d_in[14],
                            (const float*)d_in[17], (const float*)d_in[20]};
  const float* wq = (const float*)d_in[21];
  const float* bq = (const float*)d_in[22];
  const float* wk = (const float*)d_in[23];
  const float* bk = (const float*)d_in[24];
  const float* wv = (const float*)d_in[25];
  const float* bv = (const float*)d_in[26];
  const float* rel_h = (const float*)d_in[27];
  const float* rel_w = (const float*)d_in[28];
  float* out = (float*)d_out;

  float* ws = (float*)d_ws;
  size_t off = 0;
  auto alloc = [&](size_t nf) { float* p = ws + off; off += nf; return p; };
  unsigned short* Pp1 = (unsigned short*)alloc((size_t)4 * 66 * 66 * 128 / 2 + 64);
  unsigned short* Pp2 = (unsigned short*)alloc((size_t)4 * 66 * 66 * 256 / 2 + 64);
  unsigned short* Pp3 = (unsigned short*)alloc((size_t)4 * 82 * 82 * 256 / 2 + 64);
  const size_t HALF = (size_t)4 * 256 * N;
  float* t1   = alloc(HALF);                       // single full-depth conv output
  float* br   = alloc((size_t)4 * 4 * 64 * N);
  float* st1  = alloc(512);
  float* st2  = alloc(512);
  float* sta  = alloc(512);
  unsigned short* qT    = (unsigned short*)alloc((size_t)16 * N * 64 / 2);
  unsigned short* kT    = (unsigned short*)alloc((size_t)16 * N * 64 / 2);
  unsigned short* vb    = (unsigned short*)alloc((size_t)16 * N * 64 / 2);
  unsigned short* posT  = (unsigned short*)alloc((size_t)N * 64 / 2);
  unsigned short* wt1   = (unsigned short*)alloc((size_t)9 * 256 * 128 / 2);
  unsigned short* wt2   = (unsigned short*)alloc((size_t)9 * 256 * 256 / 2);
  unsigned short* wtbr  = (unsigned short*)alloc((size_t)4 * 9 * 64 * 256 / 2);
  float* o_part = alloc((size_t)4 * 16 * 64 * N);  // 67 MB
  float* mlb    = alloc((size_t)4 * 16 * 2 * N);

  hipMemsetAsync(Pp1, 0, (size_t)4 * 66 * 66 * 128 * 2, stream);
  hipMemsetAsync(Pp2, 0, (size_t)4 * 66 * 66 * 256 * 2, stream);
  hipMemsetAsync(Pp3, 0, (size_t)4 * 82 * 82 * 256 * 2, stream);
  hipMemsetAsync(wtbr, 0, (size_t)4 * 9 * 64 * 256 * 2, stream);

  // weight prep: all transposes in one launch
  wtr_all_kernel<<<5248, 256, 0, stream>>>(dc_w1, dc_w2, aspp_w[0], aspp_w[1],
                                           aspp_w[2], aspp_w[3], wt1, wt2, wtbr);

  pool_kernel<<<2048, 256, 0, stream>>>(x, Pp1);

  dcconv_kernel<128><<<dim3(32, 4, 4), 512, 0, stream>>>(Pp1, wt1, t1);
  bn_stats_dc_kernel<<<256, 256, 0, stream>>>(t1, dc_g1, dc_be1, st1);
  bn_norm_pad_kernel<<<4096, 256, 0, stream>>>(t1, st1, Pp2, 66, 1);
  dcconv_kernel<256><<<dim3(32, 4, 4), 512, 0, stream>>>(Pp2, wt2, t1);
  bn_stats_dc_kernel<<<256, 256, 0, stream>>>(t1, dc_g2, dc_be2, st2);
  bn_norm_pad_kernel<<<4096, 256, 0, stream>>>(t1, st2, Pp3, 82, 9);

  branch_kernel<<<dim3(64, 16), 256, 0, stream>>>(Pp3, wtbr, br);
  bn_stats_all_kernel<<<256, 256, 0, stream>>>(
      br, aspp_g[0], aspp_b[0], aspp_g[1], aspp_b[1],
      aspp_g[2], aspp_b[2], aspp_g[3], aspp_b[3], sta);

  qkv_kernel<<<dim3(16, 4, 16), 256, 0, stream>>>(br, sta, wq, bq, wk, bk,
                                                  wv, bv, qT, kT, vb);
  posT_kernel<<<256, 256, 0, stream>>>(rel_h, rel_w, posT);

  flash3_kernel<<<dim3(2048), 256, 0, stream>>>(qT, kT, posT, vb, o_part, mlb);
  comb_kernel<<<4096, 256, 0, stream>>>(o_part, mlb, out);
}

// Round 10
// 654.732 us; speedup vs baseline: 1.1386x; 1.1386x over previous
//
#include <hip/hip_runtime.h>
#include <math.h>

constexpr int Bn = 4;
constexpr int S  = 64;
constexpr int N  = 4096;  // S*S

#define DEV static __device__ __forceinline__

typedef __attribute__((ext_vector_type(8))) short bf16x8;
typedef __attribute__((ext_vector_type(4))) float f32x4;

DEV unsigned short bfc(float x) {  // f32 -> bf16 RNE
  unsigned u = __float_as_uint(x);
  unsigned r = (u + 0x7FFFu + ((u >> 16) & 1u)) >> 16;
  return (unsigned short)r;
}

DEV void fma4(float4& a, float s, const float4 u) {
  a.x = fmaf(s, u.x, a.x); a.y = fmaf(s, u.y, a.y);
  a.z = fmaf(s, u.z, a.z); a.w = fmaf(s, u.w, a.w);
}

// async global->LDS, 16B per lane; lds base must be wave-uniform (lane i lands at +i*16)
DEV void gload_lds16(const unsigned short* g, unsigned short* l) {
  __builtin_amdgcn_global_load_lds(
      (const __attribute__((address_space(1))) void*)g,
      (__attribute__((address_space(3))) void*)l, 16, 0, 0);
}

// pack two f32 -> one u32 of 2 bf16 (low = lo), HW RNE (matches bfc for normals)
DEV unsigned cvtpk_bf16(float lo, float hi) {
  unsigned r;
  asm("v_cvt_pk_bf16_f32 %0, %1, %2" : "=v"(r) : "v"(lo), "v"(hi));
  return r;
}
// a.hi32lanes <-> b.lo32lanes :  a' = [a.q0,a.q1,b.q0,b.q1], b' = [a.q2,a.q3,b.q2,b.q3]
DEV void pswap32(unsigned& a, unsigned& b) {
  asm("v_permlane32_swap_b32 %0, %1" : "+v"(a), "+v"(b));
}
// odd 16-rows of a <-> even 16-rows of b : a' = [a.r0,b.r0,a.r2,b.r2], b' = [a.r1,b.r1,a.r3,b.r3]
DEV void pswap16(unsigned& a, unsigned& b) {
  asm("v_permlane16_swap_b32 %0, %1" : "+v"(a), "+v"(b));
}

// ---------------- all weight transposes in ONE launch (range-decoded) ----------------
__global__ __launch_bounds__(256) void wtr_all_kernel(
    const float* __restrict__ w1, const float* __restrict__ w2,
    const float* __restrict__ a0, const float* __restrict__ a1,
    const float* __restrict__ a2, const float* __restrict__ a3,
    unsigned short* __restrict__ wt1, unsigned short* __restrict__ wt2,
    unsigned short* __restrict__ wtbr) {
  const int blk = blockIdx.x;  // 5248 total
  const float* src; unsigned short* dst; int Cin, Cout, T, base;
  if (blk < 1152)      { src = w1; dst = wt1; Cout = 256; Cin = 128; T = 9; base = 0; }
  else if (blk < 3456) { src = w2; dst = wt2; Cout = 256; Cin = 256; T = 9; base = 1152; }
  else if (blk < 3520) { src = a0; dst = wtbr + (size_t)4 * 64 * 256;
                         Cout = 64; Cin = 256; T = 1; base = 3456; }
  else if (blk < 4096) { src = a1; dst = wtbr + (size_t)1 * 9 * 64 * 256;
                         Cout = 64; Cin = 256; T = 9; base = 3520; }
  else if (blk < 4672) { src = a2; dst = wtbr + (size_t)2 * 9 * 64 * 256;
                         Cout = 64; Cin = 256; T = 9; base = 4096; }
  else                 { src = a3; dst = wtbr + (size_t)3 * 9 * 64 * 256;
                         Cout = 64; Cin = 256; T = 9; base = 4672; }
  int i = (blk - base) * 256 + threadIdx.x;
  int ci = i % Cin;
  int r  = i / Cin;
  int t  = r / Cout;
  int co = r - t * Cout;
  dst[i] = bfc(src[((size_t)co * Cin + ci) * T + t]);
}

// ---------------- maxpool 2x2 -> NHWC bf16 padded (halo=1) ----------------
__global__ __launch_bounds__(256) void pool_kernel(const float* __restrict__ x,
                                                   unsigned short* __restrict__ Pp1) {
  int i = blockIdx.x * 256 + threadIdx.x;  // 524288
  int xg = i & 15, y = (i >> 4) & 63, c = (i >> 10) & 127, b = i >> 17;
  const float* s = x + (((size_t)(b * 128 + c) * 128) + 2 * y) * 128 + 8 * xg;
  float4 u0 = *(const float4*)(s), u1 = *(const float4*)(s + 4);
  float4 u2 = *(const float4*)(s + 128), u3 = *(const float4*)(s + 132);
  float m0 = fmaxf(fmaxf(u0.x, u0.y), fmaxf(u2.x, u2.y));
  float m1 = fmaxf(fmaxf(u0.z, u0.w), fmaxf(u2.z, u2.w));
  float m2 = fmaxf(fmaxf(u1.x, u1.y), fmaxf(u3.x, u3.y));
  float m3 = fmaxf(fmaxf(u1.z, u1.w), fmaxf(u3.z, u3.w));
  unsigned short* d = Pp1 + (((size_t)b * 66 + y + 1) * 66 + xg * 4 + 1) * 128 + c;
  d[0] = bfc(m0); d[128] = bfc(m1); d[256] = bfc(m2); d[384] = bfc(m3);
}

// ---------------- dc conv: implicit GEMM, ci-split x2 (r7 config — measured best) ---
// z = b*2 + half; each half does CTOT/2 input channels; out[half] partial fp32.
// r8 (co-split) and r9 (co-64 8-wave) both regressed 40-50 us: co-split halves
// B-reuse (+453 MB input reads); 8-wave co-64 blows L1 on weights (8x re-stream
// of 32 KB/tap slabs) and halves MFMA-per-overhead. This shape: 8 MFMA per
// B-load pair, 1024 blocks = 4/CU, weights read once per block.
template <int CTOT>
__global__ __launch_bounds__(256) void dcconv_kernel(
    const unsigned short* __restrict__ in, const unsigned short* __restrict__ wt,
    float* __restrict__ out) {
  const int Wp = 66, CSEG = CTOT / 2;
  const int w = threadIdx.x >> 6, lane = threadIdx.x & 63;
  const int ln = lane & 15, quad = lane >> 4;
  const int b = blockIdx.z >> 1, h = blockIdx.z & 1, co0 = blockIdx.y * 64;
  const int n0 = blockIdx.x * 128 + w * 32;
  const unsigned short* inb = in + (size_t)b * Wp * Wp * CTOT + h * CSEG;
  const unsigned short* wth = wt + h * CSEG;
  float* outh = out + (size_t)h * 4 * 256 * N;
  size_t pix[2];
#pragma unroll
  for (int j = 0; j < 2; j++) {
    int n = n0 + j * 16 + ln;
    int y = n >> 6, x = n & 63;
    pix[j] = ((size_t)y * Wp + x) * CTOT;
  }
  f32x4 acc[4][2];
#pragma unroll
  for (int i = 0; i < 4; i++)
#pragma unroll
    for (int j = 0; j < 2; j++) acc[i][j] = (f32x4)(0.f);
#pragma unroll
  for (int ky = 0; ky < 3; ky++)
#pragma unroll
    for (int kx = 0; kx < 3; kx++) {
      const size_t toff = ((size_t)ky * Wp + kx) * CTOT;
      const unsigned short* wtap = wth + (size_t)(ky * 3 + kx) * 256 * CTOT;
      for (int kc = 0; kc < CSEG / 32; kc++) {
        const int ko = kc * 32 + quad * 8;
        bf16x8 a[4], bb[2];
#pragma unroll
        for (int i = 0; i < 4; i++)
          a[i] = *(const bf16x8*)(wtap + (size_t)(co0 + i * 16 + ln) * CTOT + ko);
#pragma unroll
        for (int j = 0; j < 2; j++)
          bb[j] = *(const bf16x8*)(inb + pix[j] + toff + ko);
#pragma unroll
        for (int i = 0; i < 4; i++)
#pragma unroll
          for (int j = 0; j < 2; j++)
            acc[i][j] = __builtin_amdgcn_mfma_f32_16x16x32_bf16(a[i], bb[j], acc[i][j], 0, 0, 0);
      }
    }
#pragma unroll
  for (int i = 0; i < 4; i++)
#pragma unroll
    for (int j = 0; j < 2; j++)
#pragma unroll
      for (int r = 0; r < 4; r++)
        outh[((size_t)(b * 256 + co0 + i * 16 + quad * 4 + r)) * N + n0 + j * 16 + ln] =
            acc[i][j][r];
}

// ---------------- all 4 ASPP branches, implicit GEMM on Pp3 (halo=9) ----------------
__global__ __launch_bounds__(256) void branch_kernel(
    const unsigned short* __restrict__ in, const unsigned short* __restrict__ wtall,
    float* __restrict__ br) {
  const int Wp = 82, halo = 9, CIN = 256;
  const int w = threadIdx.x >> 6, lane = threadIdx.x & 63;
  const int ln = lane & 15, quad = lane >> 4;
  const int bb = blockIdx.y;
  const int kbr = bb >> 2, b = bb & 3;
  const int dil = (kbr == 0) ? 1 : 3 * kbr;
  const int klo = (kbr == 0) ? 1 : 0, khi = (kbr == 0) ? 2 : 3;
  const int hd = halo - dil;
  const int cw = (w & 1) * 32, nw = (w >> 1) * 32;
  const int n0 = blockIdx.x * 64 + nw;
  const unsigned short* inb = in + (size_t)b * Wp * Wp * CIN;
  size_t pix[2];
#pragma unroll
  for (int j = 0; j < 2; j++) {
    int n = n0 + j * 16 + ln;
    int y = n >> 6, x = n & 63;
    pix[j] = ((size_t)(y + hd) * Wp + x + hd) * CIN;
  }
  f32x4 acc[2][2];
#pragma unroll
  for (int i = 0; i < 2; i++)
#pragma unroll
    for (int j = 0; j < 2; j++) acc[i][j] = (f32x4)(0.f);
  for (int ky = klo; ky < khi; ky++)
    for (int kx = klo; kx < khi; kx++) {
      const size_t toff = ((size_t)ky * Wp + kx) * dil * CIN;
      const unsigned short* wtap =
          wtall + ((size_t)kbr * 9 + ky * 3 + kx) * 64 * CIN;
      for (int kc = 0; kc < CIN / 32; kc++) {
        const int ko = kc * 32 + quad * 8;
        bf16x8 a[2], bv[2];
#pragma unroll
        for (int i = 0; i < 2; i++)
          a[i] = *(const bf16x8*)(wtap + (size_t)(cw + i * 16 + ln) * CIN + ko);
#pragma unroll
        for (int j = 0; j < 2; j++)
          bv[j] = *(const bf16x8*)(inb + pix[j] + toff + ko);
#pragma unroll
        for (int i = 0; i < 2; i++)
#pragma unroll
          for (int j = 0; j < 2; j++)
            acc[i][j] = __builtin_amdgcn_mfma_f32_16x16x32_bf16(a[i], bv[j], acc[i][j], 0, 0, 0);
      }
    }
#pragma unroll
  for (int i = 0; i < 2; i++)
#pragma unroll
    for (int j = 0; j < 2; j++)
#pragma unroll
      for (int r = 0; r < 4; r++)
        br[((size_t)bb * 64 + cw + i * 16 + quad * 4 + r) * N + n0 + j * 16 + ln] =
            acc[i][j][r];
}

// ---------------- BN stats, all 4 ASPP branches in one launch (float4 loads) --------
__global__ __launch_bounds__(256) void bn_stats_all_kernel(
    const float* __restrict__ br,
    const float* __restrict__ g0, const float* __restrict__ b0,
    const float* __restrict__ g1, const float* __restrict__ b1,
    const float* __restrict__ g2, const float* __restrict__ b2,
    const float* __restrict__ g3, const float* __restrict__ b3,
    float* __restrict__ sta) {
  const int kbr = blockIdx.x >> 6, c = blockIdx.x & 63;
  const float* gamma = kbr == 0 ? g0 : (kbr == 1 ? g1 : (kbr == 2 ? g2 : g3));
  const float* beta  = kbr == 0 ? b0 : (kbr == 1 ? b1 : (kbr == 2 ? b2 : b3));
  const float* t = br + (size_t)kbr * 1048576;
  float* ss = sta + kbr * 128;
  float s = 0.f, s2 = 0.f;
  for (int b = 0; b < Bn; b++) {
    const float* p = t + ((size_t)(b * 64 + c)) * N;
    for (int i = threadIdx.x; i < N / 4; i += 256) {
      float4 v = *(const float4*)(p + (size_t)i * 4);
      s += (v.x + v.y) + (v.z + v.w);
      s2 = fmaf(v.x, v.x, s2); s2 = fmaf(v.y, v.y, s2);
      s2 = fmaf(v.z, v.z, s2); s2 = fmaf(v.w, v.w, s2);
    }
  }
  for (int off = 32; off; off >>= 1) {
    s += __shfl_down(s, off, 64);
    s2 += __shfl_down(s2, off, 64);
  }
  __shared__ float rs[4], rs2[4];
  const int wid = threadIdx.x >> 6, lane = threadIdx.x & 63;
  if (lane == 0) { rs[wid] = s; rs2[wid] = s2; }
  __syncthreads();
  if (threadIdx.x == 0) {
    float S1 = rs[0] + rs[1] + rs[2] + rs[3];
    float S2 = rs2[0] + rs2[1] + rs2[2] + rs2[3];
    const float cnt = (float)(Bn * N);
    float mean = S1 / cnt;
    float var = S2 / cnt - mean * mean;
    float sc = gamma[c] * rsqrtf(var + 1e-5f);
    ss[2 * c] = sc;
    ss[2 * c + 1] = beta[c] - mean * sc;
  }
}

// ---------------- BN stats over sum of two partial buffers (float4 loads) -----------
__global__ __launch_bounds__(256) void bn_stats2_kernel(
    const float* __restrict__ ta, const float* __restrict__ tb,
    const float* __restrict__ gamma, const float* __restrict__ beta,
    float* __restrict__ ss, int C) {
  const int c = blockIdx.x;
  float s = 0.f, s2 = 0.f;
  for (int b = 0; b < Bn; b++) {
    const size_t base = ((size_t)(b * C + c)) * N;
    for (int i = threadIdx.x; i < N / 4; i += 256) {
      float4 va = *(const float4*)(ta + base + (size_t)i * 4);
      float4 vb = *(const float4*)(tb + base + (size_t)i * 4);
      float v0 = va.x + vb.x, v1 = va.y + vb.y;
      float v2 = va.z + vb.z, v3 = va.w + vb.w;
      s += (v0 + v1) + (v2 + v3);
      s2 = fmaf(v0, v0, s2); s2 = fmaf(v1, v1, s2);
      s2 = fmaf(v2, v2, s2); s2 = fmaf(v3, v3, s2);
    }
  }
  for (int off = 32; off; off >>= 1) {
    s += __shfl_down(s, off, 64);
    s2 += __shfl_down(s2, off, 64);
  }
  __shared__ float rs[4], rs2[4];
  const int wid = threadIdx.x >> 6, lane = threadIdx.x & 63;
  if (lane == 0) { rs[wid] = s; rs2[wid] = s2; }
  __syncthreads();
  if (threadIdx.x == 0) {
    float S1 = rs[0] + rs[1] + rs[2] + rs[3];
    float S2 = rs2[0] + rs2[1] + rs2[2] + rs2[3];
    const float cnt = (float)(Bn * N);
    float mean = S1 / cnt;
    float var = S2 / cnt - mean * mean;
    float sc = gamma[c] * rsqrtf(var + 1e-5f);
    ss[2 * c] = sc;
    ss[2 * c + 1] = beta[c] - mean * sc;
  }
}

// ---------------- BN+ReLU (sum of two partials) -> NHWC bf16 padded ----------------
__global__ __launch_bounds__(256) void bn_norm_pad2_kernel(
    const float* __restrict__ ta, const float* __restrict__ tb,
    const float* __restrict__ ss, unsigned short* __restrict__ outp,
    int Wp, int halo) {
  int i = blockIdx.x * 256 + threadIdx.x;
  int n = i & 4095, cg = (i >> 12) & 63, b = i >> 18;
  int c0 = cg * 4;
  ushort4 pk;
  float v0, v1, v2, v3;
  {
    size_t i0 = ((size_t)(b * 256 + c0 + 0)) * N + n;
    size_t i1 = i0 + N, i2 = i1 + N, i3 = i2 + N;
    v0 = fmaxf(fmaf(ta[i0] + tb[i0], ss[2 * (c0 + 0)], ss[2 * (c0 + 0) + 1]), 0.f);
    v1 = fmaxf(fmaf(ta[i1] + tb[i1], ss[2 * (c0 + 1)], ss[2 * (c0 + 1) + 1]), 0.f);
    v2 = fmaxf(fmaf(ta[i2] + tb[i2], ss[2 * (c0 + 2)], ss[2 * (c0 + 2) + 1]), 0.f);
    v3 = fmaxf(fmaf(ta[i3] + tb[i3], ss[2 * (c0 + 3)], ss[2 * (c0 + 3) + 1]), 0.f);
  }
  pk.x = bfc(v0); pk.y = bfc(v1); pk.z = bfc(v2); pk.w = bfc(v3);
  int y = n >> 6, x = n & 63;
  *(ushort4*)(outp + (((size_t)b * Wp + y + halo) * Wp + x + halo) * 256 + c0) = pk;
}

// ---------------- q/k/v 1x1 convs FUSED (one br read for all 3 projections) ----------
// Validated r8/r9 (absmax bit-stable). br read once (was 3x); per-projection
// FMA chain order identical to the split version -> bit-exact.
__global__ __launch_bounds__(256) void qkv_kernel(
    const float* __restrict__ br, const float* __restrict__ sta,
    const float* __restrict__ wq, const float* __restrict__ bq,
    const float* __restrict__ wk, const float* __restrict__ bk,
    const float* __restrict__ wv, const float* __restrict__ bvb,
    unsigned short* __restrict__ qTo, unsigned short* __restrict__ kTo,
    unsigned short* __restrict__ vbo) {
  const int bb = blockIdx.z, dg = blockIdx.y;
  __shared__ float wl[3][64 * 16];
  __shared__ float ssl[128];
  const int d0b = dg * 16;
  if (threadIdx.x < 128) ssl[threadIdx.x] = sta[(bb >> 2) * 128 + threadIdx.x];
  for (int i = threadIdx.x; i < 64 * 16; i += 256) {
    const size_t widx = (size_t)(d0b + (i & 15)) * 64 + (i >> 4);
    wl[0][i] = wq[widx];
    wl[1][i] = wk[widx];
    wl[2][i] = wv[widx];
  }
  __syncthreads();
  const int tn = threadIdx.x & 63, td = threadIdx.x >> 6;
  const int n0 = blockIdx.x * 256 + tn * 4;
  const int d0 = d0b + td * 4;
  const float* inb = br + (size_t)bb * 64 * N;
  float4 acc[3][4];
#pragma unroll
  for (int j = 0; j < 4; j++) {
    float bq_ = bq[d0 + j], bk_ = bk[d0 + j], bv_ = bvb[d0 + j];
    acc[0][j] = make_float4(bq_, bq_, bq_, bq_);
    acc[1][j] = make_float4(bk_, bk_, bk_, bk_);
    acc[2][j] = make_float4(bv_, bv_, bv_, bv_);
  }
  for (int ci = 0; ci < 64; ci++) {
    float4 u = *(const float4*)(inb + (size_t)ci * N + n0);
    const float sc = ssl[2 * ci], of = ssl[2 * ci + 1];
    u.x = fmaxf(fmaf(u.x, sc, of), 0.f);
    u.y = fmaxf(fmaf(u.y, sc, of), 0.f);
    u.z = fmaxf(fmaf(u.z, sc, of), 0.f);
    u.w = fmaxf(fmaf(u.w, sc, of), 0.f);
#pragma unroll
    for (int p = 0; p < 3; p++) {
      float4 wv4 = *(const float4*)(&wl[p][ci * 16 + td * 4]);
      fma4(acc[p][0], wv4.x, u); fma4(acc[p][1], wv4.y, u);
      fma4(acc[p][2], wv4.z, u); fma4(acc[p][3], wv4.w, u);
    }
  }
  const size_t slab = (size_t)bb * N * 64;
  // q, k: transposed [n][d] bf16
#pragma unroll
  for (int p = 0; p < 2; p++) {
    unsigned short* o = (p == 0 ? qTo : kTo) + slab;
#pragma unroll
    for (int nn = 0; nn < 4; nn++) {
      ushort4 pk;
      pk.x = bfc(((const float*)&acc[p][0])[nn]);
      pk.y = bfc(((const float*)&acc[p][1])[nn]);
      pk.z = bfc(((const float*)&acc[p][2])[nn]);
      pk.w = bfc(((const float*)&acc[p][3])[nn]);
      *(ushort4*)(o + (size_t)(n0 + nn) * 64 + d0) = pk;
    }
  }
  // v: [d][n] bf16
  {
    unsigned short* o = vbo + slab;
#pragma unroll
    for (int j = 0; j < 4; j++) {
      ushort4 pk;
      pk.x = bfc(acc[2][j].x); pk.y = bfc(acc[2][j].y);
      pk.z = bfc(acc[2][j].z); pk.w = bfc(acc[2][j].w);
      *(ushort4*)(o + (size_t)(d0 + j) * N + n0) = pk;
    }
  }
}

// ---------------- posT[n][d] = rel_w[d][h] + rel_h[d][w], bf16 ----------------
__global__ __launch_bounds__(256) void posT_kernel(
    const float* __restrict__ rel_h, const float* __restrict__ rel_w,
    unsigned short* __restrict__ posT) {
  int i = blockIdx.x * 256 + threadIdx.x;  // 65536
  int n = i >> 4, dq = (i & 15) * 4;
  int h = n >> 6, wc = n & 63;
  ushort4 pk;
  pk.x = bfc(rel_w[(dq + 0) * 64 + h] + rel_h[(dq + 0) * 64 + wc]);
  pk.y = bfc(rel_w[(dq + 1) * 64 + h] + rel_h[(dq + 1) * 64 + wc]);
  pk.z = bfc(rel_w[(dq + 2) * 64 + h] + rel_h[(dq + 2) * 64 + wc]);
  pk.w = bfc(rel_w[(dq + 3) * 64 + h] + rel_h[(dq + 3) * 64 + wc]);
  *(ushort4*)(posT + (size_t)n * 64 + dq) = pk;
}

// ---------------- flash v7: XCD-pinned slabs; V hoisted over softmax ----------------
// (unchanged since round 5)
__global__ __launch_bounds__(256, 3) void flash3_kernel(
    const unsigned short* __restrict__ qT, const unsigned short* __restrict__ kT,
    const unsigned short* __restrict__ posT, const unsigned short* __restrict__ vb,
    float* __restrict__ o_part, float* __restrict__ ml) {
  const int lin = blockIdx.x;
  const int xcd = lin & 7, slot = lin >> 3;
  const int bb = xcd * 2 + (slot & 1);
  const int rest = slot >> 1;
  const int mtile = rest & 31, split = rest >> 5;
  const size_t slab = (size_t)bb * N * 64;
  const unsigned short* qTs = qT + slab;
  const unsigned short* kTs = kT + slab;
  const unsigned short* vbs = vb + slab;
  const int w = threadIdx.x >> 6, lane = threadIdx.x & 63;
  const int ln = lane & 15, quad = lane >> 4;
  const int m0 = mtile * 128 + w * 32;  // wave's 32 m-rows (2 frags)
  // As[buf][chunk s][c-row 64][32 halfs]; chunk s: s<2 -> kT halfs (s&1)*32, s>=2 -> qT
  __shared__ __align__(16) unsigned short As[2][4][64][32];   // 32 KB

  // wave w stages chunk w (4 instrs of 1 KB covering rows j*16..j*16+15).
  // Lane i lands at LDS row i>>2, phys 16B-chunk i&3; fetch the logical chunk
  // (i&3)^((i>>3)&3) so the read-side XOR recovers linear data.
  const unsigned short* ssrc = (w < 2) ? kTs : qTs;
  const int rsub = lane >> 2;
  const int csw  = (lane & 3) ^ ((lane >> 3) & 3);
  const int ksub = (w & 1) * 32 + csw * 8;
  auto stage = [&](int c0, int bufi) {
#pragma unroll
    for (int j = 0; j < 4; j++)
      gload_lds16(ssrc + (size_t)(c0 + j * 16 + rsub) * 64 + ksub,
                  &As[bufi][w][j * 16][0]);
  };

  // m-side B fragments: s<2 -> q rows, s>=2 -> pos rows (loaded once)
  bf16x8 bq[4][2];
#pragma unroll
  for (int s = 0; s < 4; s++) {
    const unsigned short* src = (s < 2) ? qTs : posT;
#pragma unroll
    for (int mf = 0; mf < 2; mf++)
      bq[s][mf] = *(const bf16x8*)(src + (size_t)(m0 + mf * 16 + ln) * 64 +
                                   (s & 1) * 32 + quad * 8);
  }

  float m_run[2] = {-3.0e38f, -3.0e38f}, l_run[2] = {0.f, 0.f};
  f32x4 o_acc[4][2];
#pragma unroll
  for (int dt = 0; dt < 4; dt++)
#pragma unroll
    for (int mf = 0; mf < 2; mf++) o_acc[dt][mf] = (f32x4)(0.f);

  const int qsw = (quad ^ ((ln >> 1) & 3)) * 8;  // swizzled read col (halfs)
  const int cbeg = split * 1024;
  stage(cbeg, 0);
  for (int t = 0; t < 16; t++) {
    const int c0 = cbeg + t * 64;
    const int buf = t & 1;
    __syncthreads();               // staging(t) complete; buf (t+1)&1 free
    if (t < 15) stage(c0 + 64, buf ^ 1);  // overlaps compute below
    // ---- S^T from LDS: st[jt][mf][r] = St[c0+jt*16+quad*4+r][m0+mf*16+ln]
    f32x4 st[4][2];
#pragma unroll
    for (int jt = 0; jt < 4; jt++)
#pragma unroll
      for (int mf = 0; mf < 2; mf++) st[jt][mf] = (f32x4)(0.f);
    __builtin_amdgcn_s_setprio(1);
#pragma unroll
    for (int s = 0; s < 4; s++) {
#pragma unroll
      for (int jt = 0; jt < 4; jt++) {
        bf16x8 a = *(const bf16x8*)(&As[buf][s][jt * 16 + ln][qsw]);
#pragma unroll
        for (int mf = 0; mf < 2; mf++)
          st[jt][mf] = __builtin_amdgcn_mfma_f32_16x16x32_bf16(a, bq[s][mf], st[jt][mf], 0, 0, 0);
      }
    }
    __builtin_amdgcn_s_setprio(0);
    // ---- V loads issued EARLY (independent of softmax; latency hides under it)
    bf16x8 av[2][4];
#pragma unroll
    for (int tt = 0; tt < 2; tt++)
#pragma unroll
      for (int dt = 0; dt < 4; dt++)
        av[tt][dt] = *(const bf16x8*)(vbs + (size_t)(dt * 16 + ln) * N + c0 + tt * 32 + quad * 8);
    // ---- online softmax per mf (row state scalar per lane); P stays in regs
    unsigned P0[2][4], P1[2][4];  // [mf][jt]: packed bf16 pairs (c offsets 0,1 / 2,3)
#pragma unroll
    for (int mf = 0; mf < 2; mf++) {
      float mj[4];
#pragma unroll
      for (int jt = 0; jt < 4; jt++)
        mj[jt] = fmaxf(fmaxf(st[jt][mf][0], st[jt][mf][1]),
                       fmaxf(st[jt][mf][2], st[jt][mf][3]));
      float mx = fmaxf(fmaxf(mj[0], mj[1]), fmaxf(mj[2], mj[3]));
      mx = fmaxf(mx, __shfl_xor(mx, 16, 64));
      mx = fmaxf(mx, __shfl_xor(mx, 32, 64));
      // exact skip: if no lane grew, alpha==1.0 for every lane -> rescale is
      // a bit-exact identity and can be skipped entirely.
      if (!__all(mx <= m_run[mf])) {
        const float m_new = fmaxf(m_run[mf], mx);
        const float alpha = __expf(m_run[mf] - m_new);
        l_run[mf] *= alpha;
#pragma unroll
        for (int dt = 0; dt < 4; dt++)
#pragma unroll
          for (int r = 0; r < 4; r++) o_acc[dt][mf][r] *= alpha;
        m_run[mf] = m_new;
      }
      const float mc = m_run[mf];
      float psum = 0.f;
#pragma unroll
      for (int jt = 0; jt < 4; jt++) {
        float e0 = __expf(st[jt][mf][0] - mc);
        float e1 = __expf(st[jt][mf][1] - mc);
        float e2 = __expf(st[jt][mf][2] - mc);
        float e3 = __expf(st[jt][mf][3] - mc);
        psum += (e0 + e1) + (e2 + e3);
        P0[mf][jt] = cvtpk_bf16(e0, e1);
        P1[mf][jt] = cvtpk_bf16(e2, e3);
      }
      psum += __shfl_xor(psum, 16, 64);
      psum += __shfl_xor(psum, 32, 64);
      l_run[mf] += psum;
    }
    // ---- PV: O[d][m] += V[d][c] * P[c][m]
    // B-frag for (tt, quad q): c = tt*32 + q*8 + j, j=0..7, col m=ln.
    // permlane32(X,Y) -> [x0,x1,y0,y1],[x2,x3,y2,y3]; permlane16 -> [x0,x2,y0,y2],[x1,x3,y1,y3]
    __builtin_amdgcn_s_setprio(1);
#pragma unroll
    for (int tt = 0; tt < 2; tt++) {
#pragma unroll
      for (int mf = 0; mf < 2; mf++) {
        unsigned x0 = P0[mf][2 * tt], y0 = P0[mf][2 * tt + 1];
        pswap32(x0, y0); pswap16(x0, y0);   // x0 = word0, y0 = word2
        unsigned x1 = P1[mf][2 * tt], y1 = P1[mf][2 * tt + 1];
        pswap32(x1, y1); pswap16(x1, y1);   // x1 = word1, y1 = word3
        union { unsigned u[4]; bf16x8 v; } bp;
        bp.u[0] = x0; bp.u[1] = x1; bp.u[2] = y0; bp.u[3] = y1;
#pragma unroll
        for (int dt = 0; dt < 4; dt++)
          o_acc[dt][mf] = __builtin_amdgcn_mfma_f32_16x16x32_bf16(av[tt][dt], bp.v, o_acc[dt][mf], 0, 0, 0);
      }
    }
    __builtin_amdgcn_s_setprio(0);
  }
  // ---- epilogue: unnormalized partials
  float* ob = o_part + ((size_t)(split * 16 + bb) * 64) * N;
#pragma unroll
  for (int dt = 0; dt < 4; dt++)
#pragma unroll
    for (int mf = 0; mf < 2; mf++)
#pragma unroll
      for (int r = 0; r < 4; r++) {
        int d = dt * 16 + quad * 4 + r;
        ob[(size_t)d * N + m0 + mf * 16 + ln] = o_acc[dt][mf][r];
      }
  if (quad == 0) {
#pragma unroll
    for (int mf = 0; mf < 2; mf++) {
      int m = m0 + mf * 16 + ln;
      ml[((size_t)(split * 16 + bb) * 2 + 0) * N + m] = m_run[mf];
      ml[((size_t)(split * 16 + bb) * 2 + 1) * N + m] = l_run[mf];
    }
  }
}

// ---------------- combine partials -> d_out (weights computed inline) ---------------
// Validated r8/r9: identical formula/order to the former wcomb+comb pair.
__global__ __launch_bounds__(256) void comb_kernel(const float* __restrict__ o_part,
                                                   const float* __restrict__ ml,
                                                   float* __restrict__ out) {
  int i = blockIdx.x * 256 + threadIdx.x;
  int m4 = i & 1023, d = (i >> 10) & 63, bb = i >> 16;
  int kbr = bb >> 2, b = bb & 3;
  float mvv[4][4], lvv[4][4];
#pragma unroll
  for (int s = 0; s < 4; s++) {
    float4 t0 = *(const float4*)(ml + ((size_t)(s * 16 + bb) * 2 + 0) * N + m4 * 4);
    float4 t1 = *(const float4*)(ml + ((size_t)(s * 16 + bb) * 2 + 1) * N + m4 * 4);
    mvv[s][0] = t0.x; mvv[s][1] = t0.y; mvv[s][2] = t0.z; mvv[s][3] = t0.w;
    lvv[s][0] = t1.x; lvv[s][1] = t1.y; lvv[s][2] = t1.z; lvv[s][3] = t1.w;
  }
  float w4[4][4];
#pragma unroll
  for (int mm = 0; mm < 4; mm++) {
    float M = fmaxf(fmaxf(mvv[0][mm], mvv[1][mm]), fmaxf(mvv[2][mm], mvv[3][mm]));
    float wsc[4], denom = 0.f;
#pragma unroll
    for (int s = 0; s < 4; s++) {
      wsc[s] = __expf(mvv[s][mm] - M);
      denom = fmaf(wsc[s], lvv[s][mm], denom);
    }
    float inv = 1.0f / denom;
#pragma unroll
    for (int s = 0; s < 4; s++) w4[s][mm] = wsc[s] * inv;
  }
  float4 acc = make_float4(0.f, 0.f, 0.f, 0.f);
#pragma unroll
  for (int s = 0; s < 4; s++) {
    const float4 o = *(const float4*)(o_part + ((size_t)(s * 16 + bb) * 64 + d) * N + m4 * 4);
    acc.x = fmaf(o.x, w4[s][0], acc.x); acc.y = fmaf(o.y, w4[s][1], acc.y);
    acc.z = fmaf(o.z, w4[s][2], acc.z); acc.w = fmaf(o.w, w4[s][3], acc.w);
  }
  *(float4*)(out + ((size_t)(b * 256 + kbr * 64 + d)) * N + m4 * 4) = acc;
}

extern "C" void kernel_launch(void* const* d_in, const int* in_sizes, int n_in,
                              void* d_out, int out_size, void* d_ws, size_t ws_size,
                              hipStream_t stream) {
  const float* x      = (const float*)d_in[0];
  const float* dc_w1  = (const float*)d_in[1];
  const float* dc_g1  = (const float*)d_in[3];
  const float* dc_be1 = (const float*)d_in[4];
  const float* dc_w2  = (const float*)d_in[5];
  const float* dc_g2  = (const float*)d_in[7];
  const float* dc_be2 = (const float*)d_in[8];
  const float* aspp_w[4] = {(const float*)d_in[9],  (const float*)d_in[12],
                            (const float*)d_in[15], (const float*)d_in[18]};
  const float* aspp_g[4] = {(const float*)d_in[10], (const float*)d_in[13],
                            (const float*)d_in[16], (const float*)d_in[19]};
  const float* aspp_b[4] = {(const float*)d_in[11], (const float*)d_in[14],
                            (const float*)d_in[17], (const float*)d_in[20]};
  const float* wq = (const float*)d_in[21];
  const float* bq = (const float*)d_in[22];
  const float* wk = (const float*)d_in[23];
  const float* bk = (const float*)d_in[24];
  const float* wv = (const float*)d_in[25];
  const float* bv = (const float*)d_in[26];
  const float* rel_h = (const float*)d_in[27];
  const float* rel_w = (const float*)d_in[28];
  float* out = (float*)d_out;

  float* ws = (float*)d_ws;
  size_t off = 0;
  auto alloc = [&](size_t nf) { float* p = ws + off; off += nf; return p; };
  unsigned short* Pp1 = (unsigned short*)alloc((size_t)4 * 66 * 66 * 128 / 2 + 64);
  unsigned short* Pp2 = (unsigned short*)alloc((size_t)4 * 66 * 66 * 256 / 2 + 64);
  unsigned short* Pp3 = (unsigned short*)alloc((size_t)4 * 82 * 82 * 256 / 2 + 64);
  const size_t HALF = (size_t)4 * 256 * N;
  float* t1   = alloc(2 * HALF);                   // two ci-split partials (r7)
  float* br   = alloc((size_t)4 * 4 * 64 * N);
  float* st1  = alloc(512);
  float* st2  = alloc(512);
  float* sta  = alloc(512);
  unsigned short* qT    = (unsigned short*)alloc((size_t)16 * N * 64 / 2);
  unsigned short* kT    = (unsigned short*)alloc((size_t)16 * N * 64 / 2);
  unsigned short* vb    = (unsigned short*)alloc((size_t)16 * N * 64 / 2);
  unsigned short* posT  = (unsigned short*)alloc((size_t)N * 64 / 2);
  unsigned short* wt1   = (unsigned short*)alloc((size_t)9 * 256 * 128 / 2);
  unsigned short* wt2   = (unsigned short*)alloc((size_t)9 * 256 * 256 / 2);
  unsigned short* wtbr  = (unsigned short*)alloc((size_t)4 * 9 * 64 * 256 / 2);
  float* o_part = alloc((size_t)4 * 16 * 64 * N);  // 67 MB
  float* mlb    = alloc((size_t)4 * 16 * 2 * N);

  hipMemsetAsync(Pp1, 0, (size_t)4 * 66 * 66 * 128 * 2, stream);
  hipMemsetAsync(Pp2, 0, (size_t)4 * 66 * 66 * 256 * 2, stream);
  hipMemsetAsync(Pp3, 0, (size_t)4 * 82 * 82 * 256 * 2, stream);
  hipMemsetAsync(wtbr, 0, (size_t)4 * 9 * 64 * 256 * 2, stream);

  // weight prep: all transposes in one launch
  wtr_all_kernel<<<5248, 256, 0, stream>>>(dc_w1, dc_w2, aspp_w[0], aspp_w[1],
                                           aspp_w[2], aspp_w[3], wt1, wt2, wtbr);

  pool_kernel<<<2048, 256, 0, stream>>>(x, Pp1);

  dcconv_kernel<128><<<dim3(32, 4, 8), 256, 0, stream>>>(Pp1, wt1, t1);
  bn_stats2_kernel<<<256, 256, 0, stream>>>(t1, t1 + HALF, dc_g1, dc_be1, st1, 256);
  bn_norm_pad2_kernel<<<4096, 256, 0, stream>>>(t1, t1 + HALF, st1, Pp2, 66, 1);
  dcconv_kernel<256><<<dim3(32, 4, 8), 256, 0, stream>>>(Pp2, wt2, t1);
  bn_stats2_kernel<<<256, 256, 0, stream>>>(t1, t1 + HALF, dc_g2, dc_be2, st2, 256);
  bn_norm_pad2_kernel<<<4096, 256, 0, stream>>>(t1, t1 + HALF, st2, Pp3, 82, 9);

  branch_kernel<<<dim3(64, 16), 256, 0, stream>>>(Pp3, wtbr, br);
  bn_stats_all_kernel<<<256, 256, 0, stream>>>(
      br, aspp_g[0], aspp_b[0], aspp_g[1], aspp_b[1],
      aspp_g[2], aspp_b[2], aspp_g[3], aspp_b[3], sta);

  qkv_kernel<<<dim3(16, 4, 16), 256, 0, stream>>>(br, sta, wq, bq, wk, bk,
                                                  wv, bv, qT, kT, vb);
  posT_kernel<<<256, 256, 0, stream>>>(rel_h, rel_w, posT);

  flash3_kernel<<<dim3(2048), 256, 0, stream>>>(qT, kT, posT, vb, o_part, mlb);
  comb_kernel<<<4096, 256, 0, stream>>>(o_part, mlb, out);
}

// Round 11
// 653.615 us; speedup vs baseline: 1.1406x; 1.0017x over previous
//
#include <hip/hip_runtime.h>
#include <math.h>

constexpr int Bn = 4;
constexpr int S  = 64;
constexpr int N  = 4096;  // S*S

#define DEV static __device__ __forceinline__

typedef __attribute__((ext_vector_type(8))) short bf16x8;
typedef __attribute__((ext_vector_type(4))) float f32x4;

DEV unsigned short bfc(float x) {  // f32 -> bf16 RNE
  unsigned u = __float_as_uint(x);
  unsigned r = (u + 0x7FFFu + ((u >> 16) & 1u)) >> 16;
  return (unsigned short)r;
}

DEV void fma4(float4& a, float s, const float4 u) {
  a.x = fmaf(s, u.x, a.x); a.y = fmaf(s, u.y, a.y);
  a.z = fmaf(s, u.z, a.z); a.w = fmaf(s, u.w, a.w);
}

// async global->LDS, 16B per lane; lds base must be wave-uniform (lane i lands at +i*16)
DEV void gload_lds16(const unsigned short* g, unsigned short* l) {
  __builtin_amdgcn_global_load_lds(
      (const __attribute__((address_space(1))) void*)g,
      (__attribute__((address_space(3))) void*)l, 16, 0, 0);
}

// pack two f32 -> one u32 of 2 bf16 (low = lo), HW RNE (matches bfc for normals)
DEV unsigned cvtpk_bf16(float lo, float hi) {
  unsigned r;
  asm("v_cvt_pk_bf16_f32 %0, %1, %2" : "=v"(r) : "v"(lo), "v"(hi));
  return r;
}
// a.hi32lanes <-> b.lo32lanes :  a' = [a.q0,a.q1,b.q0,b.q1], b' = [a.q2,a.q3,b.q2,b.q3]
DEV void pswap32(unsigned& a, unsigned& b) {
  asm("v_permlane32_swap_b32 %0, %1" : "+v"(a), "+v"(b));
}
// odd 16-rows of a <-> even 16-rows of b : a' = [a.r0,b.r0,a.r2,b.r2], b' = [a.r1,b.r1,a.r3,b.r3]
DEV void pswap16(unsigned& a, unsigned& b) {
  asm("v_permlane16_swap_b32 %0, %1" : "+v"(a), "+v"(b));
}

// ---------------- all weight transposes in ONE launch (range-decoded) ----------------
__global__ __launch_bounds__(256) void wtr_all_kernel(
    const float* __restrict__ w1, const float* __restrict__ w2,
    const float* __restrict__ a0, const float* __restrict__ a1,
    const float* __restrict__ a2, const float* __restrict__ a3,
    unsigned short* __restrict__ wt1, unsigned short* __restrict__ wt2,
    unsigned short* __restrict__ wtbr) {
  const int blk = blockIdx.x;  // 5248 total
  const float* src; unsigned short* dst; int Cin, Cout, T, base;
  if (blk < 1152)      { src = w1; dst = wt1; Cout = 256; Cin = 128; T = 9; base = 0; }
  else if (blk < 3456) { src = w2; dst = wt2; Cout = 256; Cin = 256; T = 9; base = 1152; }
  else if (blk < 3520) { src = a0; dst = wtbr + (size_t)4 * 64 * 256;
                         Cout = 64; Cin = 256; T = 1; base = 3456; }
  else if (blk < 4096) { src = a1; dst = wtbr + (size_t)1 * 9 * 64 * 256;
                         Cout = 64; Cin = 256; T = 9; base = 3520; }
  else if (blk < 4672) { src = a2; dst = wtbr + (size_t)2 * 9 * 64 * 256;
                         Cout = 64; Cin = 256; T = 9; base = 4096; }
  else                 { src = a3; dst = wtbr + (size_t)3 * 9 * 64 * 256;
                         Cout = 64; Cin = 256; T = 9; base = 4672; }
  int i = (blk - base) * 256 + threadIdx.x;
  int ci = i % Cin;
  int r  = i / Cin;
  int t  = r / Cout;
  int co = r - t * Cout;
  dst[i] = bfc(src[((size_t)co * Cin + ci) * T + t]);
}

// ---------------- maxpool 2x2 -> NHWC bf16 padded (halo=1) ----------------
__global__ __launch_bounds__(256) void pool_kernel(const float* __restrict__ x,
                                                   unsigned short* __restrict__ Pp1) {
  int i = blockIdx.x * 256 + threadIdx.x;  // 524288
  int xg = i & 15, y = (i >> 4) & 63, c = (i >> 10) & 127, b = i >> 17;
  const float* s = x + (((size_t)(b * 128 + c) * 128) + 2 * y) * 128 + 8 * xg;
  float4 u0 = *(const float4*)(s), u1 = *(const float4*)(s + 4);
  float4 u2 = *(const float4*)(s + 128), u3 = *(const float4*)(s + 132);
  float m0 = fmaxf(fmaxf(u0.x, u0.y), fmaxf(u2.x, u2.y));
  float m1 = fmaxf(fmaxf(u0.z, u0.w), fmaxf(u2.z, u2.w));
  float m2 = fmaxf(fmaxf(u1.x, u1.y), fmaxf(u3.x, u3.y));
  float m3 = fmaxf(fmaxf(u1.z, u1.w), fmaxf(u3.z, u3.w));
  unsigned short* d = Pp1 + (((size_t)b * 66 + y + 1) * 66 + xg * 4 + 1) * 128 + c;
  d[0] = bfc(m0); d[128] = bfc(m1); d[256] = bfc(m2); d[384] = bfc(m3);
}

// ---------------- dc conv: implicit GEMM, ci-split x2 (r7 config — measured best) ---
// z = b*2 + half; each half does CTOT/2 input channels; out[half] partial fp32.
// FROZEN: r8 (co-split) and r9 (co-64 8-wave) both regressed 40-50 us.
template <int CTOT>
__global__ __launch_bounds__(256) void dcconv_kernel(
    const unsigned short* __restrict__ in, const unsigned short* __restrict__ wt,
    float* __restrict__ out) {
  const int Wp = 66, CSEG = CTOT / 2;
  const int w = threadIdx.x >> 6, lane = threadIdx.x & 63;
  const int ln = lane & 15, quad = lane >> 4;
  const int b = blockIdx.z >> 1, h = blockIdx.z & 1, co0 = blockIdx.y * 64;
  const int n0 = blockIdx.x * 128 + w * 32;
  const unsigned short* inb = in + (size_t)b * Wp * Wp * CTOT + h * CSEG;
  const unsigned short* wth = wt + h * CSEG;
  float* outh = out + (size_t)h * 4 * 256 * N;
  size_t pix[2];
#pragma unroll
  for (int j = 0; j < 2; j++) {
    int n = n0 + j * 16 + ln;
    int y = n >> 6, x = n & 63;
    pix[j] = ((size_t)y * Wp + x) * CTOT;
  }
  f32x4 acc[4][2];
#pragma unroll
  for (int i = 0; i < 4; i++)
#pragma unroll
    for (int j = 0; j < 2; j++) acc[i][j] = (f32x4)(0.f);
#pragma unroll
  for (int ky = 0; ky < 3; ky++)
#pragma unroll
    for (int kx = 0; kx < 3; kx++) {
      const size_t toff = ((size_t)ky * Wp + kx) * CTOT;
      const unsigned short* wtap = wth + (size_t)(ky * 3 + kx) * 256 * CTOT;
      for (int kc = 0; kc < CSEG / 32; kc++) {
        const int ko = kc * 32 + quad * 8;
        bf16x8 a[4], bb[2];
#pragma unroll
        for (int i = 0; i < 4; i++)
          a[i] = *(const bf16x8*)(wtap + (size_t)(co0 + i * 16 + ln) * CTOT + ko);
#pragma unroll
        for (int j = 0; j < 2; j++)
          bb[j] = *(const bf16x8*)(inb + pix[j] + toff + ko);
#pragma unroll
        for (int i = 0; i < 4; i++)
#pragma unroll
          for (int j = 0; j < 2; j++)
            acc[i][j] = __builtin_amdgcn_mfma_f32_16x16x32_bf16(a[i], bb[j], acc[i][j], 0, 0, 0);
      }
    }
#pragma unroll
  for (int i = 0; i < 4; i++)
#pragma unroll
    for (int j = 0; j < 2; j++)
#pragma unroll
      for (int r = 0; r < 4; r++)
        outh[((size_t)(b * 256 + co0 + i * 16 + quad * 4 + r)) * N + n0 + j * 16 + ln] =
            acc[i][j][r];
}

// ---------------- all 4 ASPP branches, implicit GEMM on Pp3 (halo=9) ----------------
__global__ __launch_bounds__(256) void branch_kernel(
    const unsigned short* __restrict__ in, const unsigned short* __restrict__ wtall,
    float* __restrict__ br) {
  const int Wp = 82, halo = 9, CIN = 256;
  const int w = threadIdx.x >> 6, lane = threadIdx.x & 63;
  const int ln = lane & 15, quad = lane >> 4;
  const int bb = blockIdx.y;
  const int kbr = bb >> 2, b = bb & 3;
  const int dil = (kbr == 0) ? 1 : 3 * kbr;
  const int klo = (kbr == 0) ? 1 : 0, khi = (kbr == 0) ? 2 : 3;
  const int hd = halo - dil;
  const int cw = (w & 1) * 32, nw = (w >> 1) * 32;
  const int n0 = blockIdx.x * 64 + nw;
  const unsigned short* inb = in + (size_t)b * Wp * Wp * CIN;
  size_t pix[2];
#pragma unroll
  for (int j = 0; j < 2; j++) {
    int n = n0 + j * 16 + ln;
    int y = n >> 6, x = n & 63;
    pix[j] = ((size_t)(y + hd) * Wp + x + hd) * CIN;
  }
  f32x4 acc[2][2];
#pragma unroll
  for (int i = 0; i < 2; i++)
#pragma unroll
    for (int j = 0; j < 2; j++) acc[i][j] = (f32x4)(0.f);
  for (int ky = klo; ky < khi; ky++)
    for (int kx = klo; kx < khi; kx++) {
      const size_t toff = ((size_t)ky * Wp + kx) * dil * CIN;
      const unsigned short* wtap =
          wtall + ((size_t)kbr * 9 + ky * 3 + kx) * 64 * CIN;
      for (int kc = 0; kc < CIN / 32; kc++) {
        const int ko = kc * 32 + quad * 8;
        bf16x8 a[2], bv[2];
#pragma unroll
        for (int i = 0; i < 2; i++)
          a[i] = *(const bf16x8*)(wtap + (size_t)(cw + i * 16 + ln) * CIN + ko);
#pragma unroll
        for (int j = 0; j < 2; j++)
          bv[j] = *(const bf16x8*)(inb + pix[j] + toff + ko);
#pragma unroll
        for (int i = 0; i < 2; i++)
#pragma unroll
          for (int j = 0; j < 2; j++)
            acc[i][j] = __builtin_amdgcn_mfma_f32_16x16x32_bf16(a[i], bv[j], acc[i][j], 0, 0, 0);
      }
    }
#pragma unroll
  for (int i = 0; i < 2; i++)
#pragma unroll
    for (int j = 0; j < 2; j++)
#pragma unroll
      for (int r = 0; r < 4; r++)
        br[((size_t)bb * 64 + cw + i * 16 + quad * 4 + r) * N + n0 + j * 16 + ln] =
            acc[i][j][r];
}

// ---------------- BN stats, all 4 ASPP branches in one launch (float4 loads) --------
__global__ __launch_bounds__(256) void bn_stats_all_kernel(
    const float* __restrict__ br,
    const float* __restrict__ g0, const float* __restrict__ b0,
    const float* __restrict__ g1, const float* __restrict__ b1,
    const float* __restrict__ g2, const float* __restrict__ b2,
    const float* __restrict__ g3, const float* __restrict__ b3,
    float* __restrict__ sta) {
  const int kbr = blockIdx.x >> 6, c = blockIdx.x & 63;
  const float* gamma = kbr == 0 ? g0 : (kbr == 1 ? g1 : (kbr == 2 ? g2 : g3));
  const float* beta  = kbr == 0 ? b0 : (kbr == 1 ? b1 : (kbr == 2 ? b2 : b3));
  const float* t = br + (size_t)kbr * 1048576;
  float* ss = sta + kbr * 128;
  float s = 0.f, s2 = 0.f;
  for (int b = 0; b < Bn; b++) {
    const float* p = t + ((size_t)(b * 64 + c)) * N;
    for (int i = threadIdx.x; i < N / 4; i += 256) {
      float4 v = *(const float4*)(p + (size_t)i * 4);
      s += (v.x + v.y) + (v.z + v.w);
      s2 = fmaf(v.x, v.x, s2); s2 = fmaf(v.y, v.y, s2);
      s2 = fmaf(v.z, v.z, s2); s2 = fmaf(v.w, v.w, s2);
    }
  }
  for (int off = 32; off; off >>= 1) {
    s += __shfl_down(s, off, 64);
    s2 += __shfl_down(s2, off, 64);
  }
  __shared__ float rs[4], rs2[4];
  const int wid = threadIdx.x >> 6, lane = threadIdx.x & 63;
  if (lane == 0) { rs[wid] = s; rs2[wid] = s2; }
  __syncthreads();
  if (threadIdx.x == 0) {
    float S1 = rs[0] + rs[1] + rs[2] + rs[3];
    float S2 = rs2[0] + rs2[1] + rs2[2] + rs2[3];
    const float cnt = (float)(Bn * N);
    float mean = S1 / cnt;
    float var = S2 / cnt - mean * mean;
    float sc = gamma[c] * rsqrtf(var + 1e-5f);
    ss[2 * c] = sc;
    ss[2 * c + 1] = beta[c] - mean * sc;
  }
}

// ---------------- BN stats over sum of two partial buffers (float4 loads) -----------
__global__ __launch_bounds__(256) void bn_stats2_kernel(
    const float* __restrict__ ta, const float* __restrict__ tb,
    const float* __restrict__ gamma, const float* __restrict__ beta,
    float* __restrict__ ss, int C) {
  const int c = blockIdx.x;
  float s = 0.f, s2 = 0.f;
  for (int b = 0; b < Bn; b++) {
    const size_t base = ((size_t)(b * C + c)) * N;
    for (int i = threadIdx.x; i < N / 4; i += 256) {
      float4 va = *(const float4*)(ta + base + (size_t)i * 4);
      float4 vb = *(const float4*)(tb + base + (size_t)i * 4);
      float v0 = va.x + vb.x, v1 = va.y + vb.y;
      float v2 = va.z + vb.z, v3 = va.w + vb.w;
      s += (v0 + v1) + (v2 + v3);
      s2 = fmaf(v0, v0, s2); s2 = fmaf(v1, v1, s2);
      s2 = fmaf(v2, v2, s2); s2 = fmaf(v3, v3, s2);
    }
  }
  for (int off = 32; off; off >>= 1) {
    s += __shfl_down(s, off, 64);
    s2 += __shfl_down(s2, off, 64);
  }
  __shared__ float rs[4], rs2[4];
  const int wid = threadIdx.x >> 6, lane = threadIdx.x & 63;
  if (lane == 0) { rs[wid] = s; rs2[wid] = s2; }
  __syncthreads();
  if (threadIdx.x == 0) {
    float S1 = rs[0] + rs[1] + rs[2] + rs[3];
    float S2 = rs2[0] + rs2[1] + rs2[2] + rs2[3];
    const float cnt = (float)(Bn * N);
    float mean = S1 / cnt;
    float var = S2 / cnt - mean * mean;
    float sc = gamma[c] * rsqrtf(var + 1e-5f);
    ss[2 * c] = sc;
    ss[2 * c + 1] = beta[c] - mean * sc;
  }
}

// ---------------- BN+ReLU (sum of two partials) -> NHWC bf16 padded ----------------
__global__ __launch_bounds__(256) void bn_norm_pad2_kernel(
    const float* __restrict__ ta, const float* __restrict__ tb,
    const float* __restrict__ ss, unsigned short* __restrict__ outp,
    int Wp, int halo) {
  int i = blockIdx.x * 256 + threadIdx.x;
  int n = i & 4095, cg = (i >> 12) & 63, b = i >> 18;
  int c0 = cg * 4;
  ushort4 pk;
  float v0, v1, v2, v3;
  {
    size_t i0 = ((size_t)(b * 256 + c0 + 0)) * N + n;
    size_t i1 = i0 + N, i2 = i1 + N, i3 = i2 + N;
    v0 = fmaxf(fmaf(ta[i0] + tb[i0], ss[2 * (c0 + 0)], ss[2 * (c0 + 0) + 1]), 0.f);
    v1 = fmaxf(fmaf(ta[i1] + tb[i1], ss[2 * (c0 + 1)], ss[2 * (c0 + 1) + 1]), 0.f);
    v2 = fmaxf(fmaf(ta[i2] + tb[i2], ss[2 * (c0 + 2)], ss[2 * (c0 + 2) + 1]), 0.f);
    v3 = fmaxf(fmaf(ta[i3] + tb[i3], ss[2 * (c0 + 3)], ss[2 * (c0 + 3) + 1]), 0.f);
  }
  pk.x = bfc(v0); pk.y = bfc(v1); pk.z = bfc(v2); pk.w = bfc(v3);
  int y = n >> 6, x = n & 63;
  *(ushort4*)(outp + (((size_t)b * Wp + y + halo) * Wp + x + halo) * 256 + c0) = pk;
}

// ---------------- q/k/v 1x1 convs FUSED (one br read for all 3 projections) ----------
__global__ __launch_bounds__(256) void qkv_kernel(
    const float* __restrict__ br, const float* __restrict__ sta,
    const float* __restrict__ wq, const float* __restrict__ bq,
    const float* __restrict__ wk, const float* __restrict__ bk,
    const float* __restrict__ wv, const float* __restrict__ bvb,
    unsigned short* __restrict__ qTo, unsigned short* __restrict__ kTo,
    unsigned short* __restrict__ vbo) {
  const int bb = blockIdx.z, dg = blockIdx.y;
  __shared__ float wl[3][64 * 16];
  __shared__ float ssl[128];
  const int d0b = dg * 16;
  if (threadIdx.x < 128) ssl[threadIdx.x] = sta[(bb >> 2) * 128 + threadIdx.x];
  for (int i = threadIdx.x; i < 64 * 16; i += 256) {
    const size_t widx = (size_t)(d0b + (i & 15)) * 64 + (i >> 4);
    wl[0][i] = wq[widx];
    wl[1][i] = wk[widx];
    wl[2][i] = wv[widx];
  }
  __syncthreads();
  const int tn = threadIdx.x & 63, td = threadIdx.x >> 6;
  const int n0 = blockIdx.x * 256 + tn * 4;
  const int d0 = d0b + td * 4;
  const float* inb = br + (size_t)bb * 64 * N;
  float4 acc[3][4];
#pragma unroll
  for (int j = 0; j < 4; j++) {
    float bq_ = bq[d0 + j], bk_ = bk[d0 + j], bv_ = bvb[d0 + j];
    acc[0][j] = make_float4(bq_, bq_, bq_, bq_);
    acc[1][j] = make_float4(bk_, bk_, bk_, bk_);
    acc[2][j] = make_float4(bv_, bv_, bv_, bv_);
  }
  for (int ci = 0; ci < 64; ci++) {
    float4 u = *(const float4*)(inb + (size_t)ci * N + n0);
    const float sc = ssl[2 * ci], of = ssl[2 * ci + 1];
    u.x = fmaxf(fmaf(u.x, sc, of), 0.f);
    u.y = fmaxf(fmaf(u.y, sc, of), 0.f);
    u.z = fmaxf(fmaf(u.z, sc, of), 0.f);
    u.w = fmaxf(fmaf(u.w, sc, of), 0.f);
#pragma unroll
    for (int p = 0; p < 3; p++) {
      float4 wv4 = *(const float4*)(&wl[p][ci * 16 + td * 4]);
      fma4(acc[p][0], wv4.x, u); fma4(acc[p][1], wv4.y, u);
      fma4(acc[p][2], wv4.z, u); fma4(acc[p][3], wv4.w, u);
    }
  }
  const size_t slab = (size_t)bb * N * 64;
  // q, k: transposed [n][d] bf16
#pragma unroll
  for (int p = 0; p < 2; p++) {
    unsigned short* o = (p == 0 ? qTo : kTo) + slab;
#pragma unroll
    for (int nn = 0; nn < 4; nn++) {
      ushort4 pk;
      pk.x = bfc(((const float*)&acc[p][0])[nn]);
      pk.y = bfc(((const float*)&acc[p][1])[nn]);
      pk.z = bfc(((const float*)&acc[p][2])[nn]);
      pk.w = bfc(((const float*)&acc[p][3])[nn]);
      *(ushort4*)(o + (size_t)(n0 + nn) * 64 + d0) = pk;
    }
  }
  // v: [d][n] bf16
  {
    unsigned short* o = vbo + slab;
#pragma unroll
    for (int j = 0; j < 4; j++) {
      ushort4 pk;
      pk.x = bfc(acc[2][j].x); pk.y = bfc(acc[2][j].y);
      pk.z = bfc(acc[2][j].z); pk.w = bfc(acc[2][j].w);
      *(ushort4*)(o + (size_t)(d0 + j) * N + n0) = pk;
    }
  }
}

// ---------------- posT[n][d] = rel_w[d][h] + rel_h[d][w], bf16 ----------------
__global__ __launch_bounds__(256) void posT_kernel(
    const float* __restrict__ rel_h, const float* __restrict__ rel_w,
    unsigned short* __restrict__ posT) {
  int i = blockIdx.x * 256 + threadIdx.x;  // 65536
  int n = i >> 4, dq = (i & 15) * 4;
  int h = n >> 6, wc = n & 63;
  ushort4 pk;
  pk.x = bfc(rel_w[(dq + 0) * 64 + h] + rel_h[(dq + 0) * 64 + wc]);
  pk.y = bfc(rel_w[(dq + 1) * 64 + h] + rel_h[(dq + 1) * 64 + wc]);
  pk.z = bfc(rel_w[(dq + 2) * 64 + h] + rel_h[(dq + 2) * 64 + wc]);
  pk.w = bfc(rel_w[(dq + 3) * 64 + h] + rel_h[(dq + 3) * 64 + wc]);
  *(ushort4*)(posT + (size_t)n * 64 + dq) = pk;
}

// ---------------- flash v8: 2 c-splits (was 4) — halves the o_part round-trip -------
// grid 1024 = 8 xcd x {2 bb} x 32 mtiles x 2 splits. Each block walks 32 c-tiles
// (2048 cols): same total FLOPs, half the partial-buffer traffic (o_part
// 67->33.5 MB, ml 4.2->2.1), prologue amortized 2x. Occupancy: 1024 blocks =
// 4/CU needed, LDS allows 5, VGPR 80 allows 6 waves/SIMD -> fully resident.
// Numerics: fp32 reassociation only (32-tile online chain + 2-way combine).
__global__ __launch_bounds__(256, 3) void flash3_kernel(
    const unsigned short* __restrict__ qT, const unsigned short* __restrict__ kT,
    const unsigned short* __restrict__ posT, const unsigned short* __restrict__ vb,
    float* __restrict__ o_part, float* __restrict__ ml) {
  const int lin = blockIdx.x;
  const int xcd = lin & 7, slot = lin >> 3;
  const int bb = xcd * 2 + (slot & 1);
  const int rest = slot >> 1;
  const int mtile = rest & 31, split = rest >> 5;   // split in {0,1}
  const size_t slab = (size_t)bb * N * 64;
  const unsigned short* qTs = qT + slab;
  const unsigned short* kTs = kT + slab;
  const unsigned short* vbs = vb + slab;
  const int w = threadIdx.x >> 6, lane = threadIdx.x & 63;
  const int ln = lane & 15, quad = lane >> 4;
  const int m0 = mtile * 128 + w * 32;  // wave's 32 m-rows (2 frags)
  // As[buf][chunk s][c-row 64][32 halfs]; chunk s: s<2 -> kT halfs (s&1)*32, s>=2 -> qT
  __shared__ __align__(16) unsigned short As[2][4][64][32];   // 32 KB

  // wave w stages chunk w (4 instrs of 1 KB covering rows j*16..j*16+15).
  // Lane i lands at LDS row i>>2, phys 16B-chunk i&3; fetch the logical chunk
  // (i&3)^((i>>3)&3) so the read-side XOR recovers linear data.
  const unsigned short* ssrc = (w < 2) ? kTs : qTs;
  const int rsub = lane >> 2;
  const int csw  = (lane & 3) ^ ((lane >> 3) & 3);
  const int ksub = (w & 1) * 32 + csw * 8;
  auto stage = [&](int c0, int bufi) {
#pragma unroll
    for (int j = 0; j < 4; j++)
      gload_lds16(ssrc + (size_t)(c0 + j * 16 + rsub) * 64 + ksub,
                  &As[bufi][w][j * 16][0]);
  };

  // m-side B fragments: s<2 -> q rows, s>=2 -> pos rows (loaded once)
  bf16x8 bq[4][2];
#pragma unroll
  for (int s = 0; s < 4; s++) {
    const unsigned short* src = (s < 2) ? qTs : posT;
#pragma unroll
    for (int mf = 0; mf < 2; mf++)
      bq[s][mf] = *(const bf16x8*)(src + (size_t)(m0 + mf * 16 + ln) * 64 +
                                   (s & 1) * 32 + quad * 8);
  }

  float m_run[2] = {-3.0e38f, -3.0e38f}, l_run[2] = {0.f, 0.f};
  f32x4 o_acc[4][2];
#pragma unroll
  for (int dt = 0; dt < 4; dt++)
#pragma unroll
    for (int mf = 0; mf < 2; mf++) o_acc[dt][mf] = (f32x4)(0.f);

  const int qsw = (quad ^ ((ln >> 1) & 3)) * 8;  // swizzled read col (halfs)
  const int cbeg = split * 2048;
  stage(cbeg, 0);
  for (int t = 0; t < 32; t++) {
    const int c0 = cbeg + t * 64;
    const int buf = t & 1;
    __syncthreads();               // staging(t) complete; buf (t+1)&1 free
    if (t < 31) stage(c0 + 64, buf ^ 1);  // overlaps compute below
    // ---- S^T from LDS: st[jt][mf][r] = St[c0+jt*16+quad*4+r][m0+mf*16+ln]
    f32x4 st[4][2];
#pragma unroll
    for (int jt = 0; jt < 4; jt++)
#pragma unroll
      for (int mf = 0; mf < 2; mf++) st[jt][mf] = (f32x4)(0.f);
    __builtin_amdgcn_s_setprio(1);
#pragma unroll
    for (int s = 0; s < 4; s++) {
#pragma unroll
      for (int jt = 0; jt < 4; jt++) {
        bf16x8 a = *(const bf16x8*)(&As[buf][s][jt * 16 + ln][qsw]);
#pragma unroll
        for (int mf = 0; mf < 2; mf++)
          st[jt][mf] = __builtin_amdgcn_mfma_f32_16x16x32_bf16(a, bq[s][mf], st[jt][mf], 0, 0, 0);
      }
    }
    __builtin_amdgcn_s_setprio(0);
    // ---- V loads issued EARLY (independent of softmax; latency hides under it)
    bf16x8 av[2][4];
#pragma unroll
    for (int tt = 0; tt < 2; tt++)
#pragma unroll
      for (int dt = 0; dt < 4; dt++)
        av[tt][dt] = *(const bf16x8*)(vbs + (size_t)(dt * 16 + ln) * N + c0 + tt * 32 + quad * 8);
    // ---- online softmax per mf (row state scalar per lane); P stays in regs
    unsigned P0[2][4], P1[2][4];  // [mf][jt]: packed bf16 pairs (c offsets 0,1 / 2,3)
#pragma unroll
    for (int mf = 0; mf < 2; mf++) {
      float mj[4];
#pragma unroll
      for (int jt = 0; jt < 4; jt++)
        mj[jt] = fmaxf(fmaxf(st[jt][mf][0], st[jt][mf][1]),
                       fmaxf(st[jt][mf][2], st[jt][mf][3]));
      float mx = fmaxf(fmaxf(mj[0], mj[1]), fmaxf(mj[2], mj[3]));
      mx = fmaxf(mx, __shfl_xor(mx, 16, 64));
      mx = fmaxf(mx, __shfl_xor(mx, 32, 64));
      // exact skip: if no lane grew, alpha==1.0 for every lane -> rescale is
      // a bit-exact identity and can be skipped entirely.
      if (!__all(mx <= m_run[mf])) {
        const float m_new = fmaxf(m_run[mf], mx);
        const float alpha = __expf(m_run[mf] - m_new);
        l_run[mf] *= alpha;
#pragma unroll
        for (int dt = 0; dt < 4; dt++)
#pragma unroll
          for (int r = 0; r < 4; r++) o_acc[dt][mf][r] *= alpha;
        m_run[mf] = m_new;
      }
      const float mc = m_run[mf];
      float psum = 0.f;
#pragma unroll
      for (int jt = 0; jt < 4; jt++) {
        float e0 = __expf(st[jt][mf][0] - mc);
        float e1 = __expf(st[jt][mf][1] - mc);
        float e2 = __expf(st[jt][mf][2] - mc);
        float e3 = __expf(st[jt][mf][3] - mc);
        psum += (e0 + e1) + (e2 + e3);
        P0[mf][jt] = cvtpk_bf16(e0, e1);
        P1[mf][jt] = cvtpk_bf16(e2, e3);
      }
      psum += __shfl_xor(psum, 16, 64);
      psum += __shfl_xor(psum, 32, 64);
      l_run[mf] += psum;
    }
    // ---- PV: O[d][m] += V[d][c] * P[c][m]
    // B-frag for (tt, quad q): c = tt*32 + q*8 + j, j=0..7, col m=ln.
    // permlane32(X,Y) -> [x0,x1,y0,y1],[x2,x3,y2,y3]; permlane16 -> [x0,x2,y0,y2],[x1,x3,y1,y3]
    __builtin_amdgcn_s_setprio(1);
#pragma unroll
    for (int tt = 0; tt < 2; tt++) {
#pragma unroll
      for (int mf = 0; mf < 2; mf++) {
        unsigned x0 = P0[mf][2 * tt], y0 = P0[mf][2 * tt + 1];
        pswap32(x0, y0); pswap16(x0, y0);   // x0 = word0, y0 = word2
        unsigned x1 = P1[mf][2 * tt], y1 = P1[mf][2 * tt + 1];
        pswap32(x1, y1); pswap16(x1, y1);   // x1 = word1, y1 = word3
        union { unsigned u[4]; bf16x8 v; } bp;
        bp.u[0] = x0; bp.u[1] = x1; bp.u[2] = y0; bp.u[3] = y1;
#pragma unroll
        for (int dt = 0; dt < 4; dt++)
          o_acc[dt][mf] = __builtin_amdgcn_mfma_f32_16x16x32_bf16(av[tt][dt], bp.v, o_acc[dt][mf], 0, 0, 0);
      }
    }
    __builtin_amdgcn_s_setprio(0);
  }
  // ---- epilogue: unnormalized partials
  float* ob = o_part + ((size_t)(split * 16 + bb) * 64) * N;
#pragma unroll
  for (int dt = 0; dt < 4; dt++)
#pragma unroll
    for (int mf = 0; mf < 2; mf++)
#pragma unroll
      for (int r = 0; r < 4; r++) {
        int d = dt * 16 + quad * 4 + r;
        ob[(size_t)d * N + m0 + mf * 16 + ln] = o_acc[dt][mf][r];
      }
  if (quad == 0) {
#pragma unroll
    for (int mf = 0; mf < 2; mf++) {
      int m = m0 + mf * 16 + ln;
      ml[((size_t)(split * 16 + bb) * 2 + 0) * N + m] = m_run[mf];
      ml[((size_t)(split * 16 + bb) * 2 + 1) * N + m] = l_run[mf];
    }
  }
}

// ---------------- combine 2 partials -> d_out (weights computed inline) -------------
__global__ __launch_bounds__(256) void comb_kernel(const float* __restrict__ o_part,
                                                   const float* __restrict__ ml,
                                                   float* __restrict__ out) {
  int i = blockIdx.x * 256 + threadIdx.x;
  int m4 = i & 1023, d = (i >> 10) & 63, bb = i >> 16;
  int kbr = bb >> 2, b = bb & 3;
  float mvv[2][4], lvv[2][4];
#pragma unroll
  for (int s = 0; s < 2; s++) {
    float4 t0 = *(const float4*)(ml + ((size_t)(s * 16 + bb) * 2 + 0) * N + m4 * 4);
    float4 t1 = *(const float4*)(ml + ((size_t)(s * 16 + bb) * 2 + 1) * N + m4 * 4);
    mvv[s][0] = t0.x; mvv[s][1] = t0.y; mvv[s][2] = t0.z; mvv[s][3] = t0.w;
    lvv[s][0] = t1.x; lvv[s][1] = t1.y; lvv[s][2] = t1.z; lvv[s][3] = t1.w;
  }
  float w4[2][4];
#pragma unroll
  for (int mm = 0; mm < 4; mm++) {
    float M = fmaxf(mvv[0][mm], mvv[1][mm]);
    float wsc[2], denom = 0.f;
#pragma unroll
    for (int s = 0; s < 2; s++) {
      wsc[s] = __expf(mvv[s][mm] - M);
      denom = fmaf(wsc[s], lvv[s][mm], denom);
    }
    float inv = 1.0f / denom;
#pragma unroll
    for (int s = 0; s < 2; s++) w4[s][mm] = wsc[s] * inv;
  }
  float4 acc = make_float4(0.f, 0.f, 0.f, 0.f);
#pragma unroll
  for (int s = 0; s < 2; s++) {
    const float4 o = *(const float4*)(o_part + ((size_t)(s * 16 + bb) * 64 + d) * N + m4 * 4);
    acc.x = fmaf(o.x, w4[s][0], acc.x); acc.y = fmaf(o.y, w4[s][1], acc.y);
    acc.z = fmaf(o.z, w4[s][2], acc.z); acc.w = fmaf(o.w, w4[s][3], acc.w);
  }
  *(float4*)(out + ((size_t)(b * 256 + kbr * 64 + d)) * N + m4 * 4) = acc;
}

extern "C" void kernel_launch(void* const* d_in, const int* in_sizes, int n_in,
                              void* d_out, int out_size, void* d_ws, size_t ws_size,
                              hipStream_t stream) {
  const float* x      = (const float*)d_in[0];
  const float* dc_w1  = (const float*)d_in[1];
  const float* dc_g1  = (const float*)d_in[3];
  const float* dc_be1 = (const float*)d_in[4];
  const float* dc_w2  = (const float*)d_in[5];
  const float* dc_g2  = (const float*)d_in[7];
  const float* dc_be2 = (const float*)d_in[8];
  const float* aspp_w[4] = {(const float*)d_in[9],  (const float*)d_in[12],
                            (const float*)d_in[15], (const float*)d_in[18]};
  const float* aspp_g[4] = {(const float*)d_in[10], (const float*)d_in[13],
                            (const float*)d_in[16], (const float*)d_in[19]};
  const float* aspp_b[4] = {(const float*)d_in[11], (const float*)d_in[14],
                            (const float*)d_in[17], (const float*)d_in[20]};
  const float* wq = (const float*)d_in[21];
  const float* bq = (const float*)d_in[22];
  const float* wk = (const float*)d_in[23];
  const float* bk = (const float*)d_in[24];
  const float* wv = (const float*)d_in[25];
  const float* bv = (const float*)d_in[26];
  const float* rel_h = (const float*)d_in[27];
  const float* rel_w = (const float*)d_in[28];
  float* out = (float*)d_out;

  float* ws = (float*)d_ws;
  size_t off = 0;
  auto alloc = [&](size_t nf) { float* p = ws + off; off += nf; return p; };
  unsigned short* Pp1 = (unsigned short*)alloc((size_t)4 * 66 * 66 * 128 / 2 + 64);
  unsigned short* Pp2 = (unsigned short*)alloc((size_t)4 * 66 * 66 * 256 / 2 + 64);
  unsigned short* Pp3 = (unsigned short*)alloc((size_t)4 * 82 * 82 * 256 / 2 + 64);
  const size_t HALF = (size_t)4 * 256 * N;
  float* t1   = alloc(2 * HALF);                   // two ci-split partials (r7)
  float* br   = alloc((size_t)4 * 4 * 64 * N);
  float* st1  = alloc(512);
  float* st2  = alloc(512);
  float* sta  = alloc(512);
  unsigned short* qT    = (unsigned short*)alloc((size_t)16 * N * 64 / 2);
  unsigned short* kT    = (unsigned short*)alloc((size_t)16 * N * 64 / 2);
  unsigned short* vb    = (unsigned short*)alloc((size_t)16 * N * 64 / 2);
  unsigned short* posT  = (unsigned short*)alloc((size_t)N * 64 / 2);
  unsigned short* wt1   = (unsigned short*)alloc((size_t)9 * 256 * 128 / 2);
  unsigned short* wt2   = (unsigned short*)alloc((size_t)9 * 256 * 256 / 2);
  unsigned short* wtbr  = (unsigned short*)alloc((size_t)4 * 9 * 64 * 256 / 2);
  float* o_part = alloc((size_t)2 * 16 * 64 * N);  // 33.5 MB (2 splits)
  float* mlb    = alloc((size_t)2 * 16 * 2 * N);

  hipMemsetAsync(Pp1, 0, (size_t)4 * 66 * 66 * 128 * 2, stream);
  hipMemsetAsync(Pp2, 0, (size_t)4 * 66 * 66 * 256 * 2, stream);
  hipMemsetAsync(Pp3, 0, (size_t)4 * 82 * 82 * 256 * 2, stream);
  // wtbr memset dropped: branch reads only kbr0 tap 4 (written by wtr_all)
  // plus kbr1-3's 9 taps (all written) — the other kbr0 slots are dead.

  // weight prep: all transposes in one launch
  wtr_all_kernel<<<5248, 256, 0, stream>>>(dc_w1, dc_w2, aspp_w[0], aspp_w[1],
                                           aspp_w[2], aspp_w[3], wt1, wt2, wtbr);

  pool_kernel<<<2048, 256, 0, stream>>>(x, Pp1);

  dcconv_kernel<128><<<dim3(32, 4, 8), 256, 0, stream>>>(Pp1, wt1, t1);
  bn_stats2_kernel<<<256, 256, 0, stream>>>(t1, t1 + HALF, dc_g1, dc_be1, st1, 256);
  bn_norm_pad2_kernel<<<4096, 256, 0, stream>>>(t1, t1 + HALF, st1, Pp2, 66, 1);
  dcconv_kernel<256><<<dim3(32, 4, 8), 256, 0, stream>>>(Pp2, wt2, t1);
  bn_stats2_kernel<<<256, 256, 0, stream>>>(t1, t1 + HALF, dc_g2, dc_be2, st2, 256);
  bn_norm_pad2_kernel<<<4096, 256, 0, stream>>>(t1, t1 + HALF, st2, Pp3, 82, 9);

  branch_kernel<<<dim3(64, 16), 256, 0, stream>>>(Pp3, wtbr, br);
  bn_stats_all_kernel<<<256, 256, 0, stream>>>(
      br, aspp_g[0], aspp_b[0], aspp_g[1], aspp_b[1],
      aspp_g[2], aspp_b[2], aspp_g[3], aspp_b[3], sta);

  qkv_kernel<<<dim3(16, 4, 16), 256, 0, stream>>>(br, sta, wq, bq, wk, bk,
                                                  wv, bv, qT, kT, vb);
  posT_kernel<<<256, 256, 0, stream>>>(rel_h, rel_w, posT);

  flash3_kernel<<<dim3(1024), 256, 0, stream>>>(qT, kT, posT, vb, o_part, mlb);
  comb_kernel<<<4096, 256, 0, stream>>>(o_part, mlb, out);
}

// Round 13
// 648.199 us; speedup vs baseline: 1.1501x; 1.0084x over previous
//
#include <hip/hip_runtime.h>
#include <math.h>

constexpr int Bn = 4;
constexpr int S  = 64;
constexpr int N  = 4096;  // S*S

#define DEV static __device__ __forceinline__

typedef __attribute__((ext_vector_type(8))) short bf16x8;
typedef __attribute__((ext_vector_type(4))) float f32x4;

DEV unsigned short bfc(float x) {  // f32 -> bf16 RNE
  unsigned u = __float_as_uint(x);
  unsigned r = (u + 0x7FFFu + ((u >> 16) & 1u)) >> 16;
  return (unsigned short)r;
}

DEV void fma4(float4& a, float s, const float4 u) {
  a.x = fmaf(s, u.x, a.x); a.y = fmaf(s, u.y, a.y);
  a.z = fmaf(s, u.z, a.z); a.w = fmaf(s, u.w, a.w);
}

// async global->LDS, 16B per lane; lds base must be wave-uniform (lane i lands at +i*16)
DEV void gload_lds16(const unsigned short* g, unsigned short* l) {
  __builtin_amdgcn_global_load_lds(
      (const __attribute__((address_space(1))) void*)g,
      (__attribute__((address_space(3))) void*)l, 16, 0, 0);
}

// pack two f32 -> one u32 of 2 bf16 (low = lo), HW RNE (matches bfc for normals)
DEV unsigned cvtpk_bf16(float lo, float hi) {
  unsigned r;
  asm("v_cvt_pk_bf16_f32 %0, %1, %2" : "=v"(r) : "v"(lo), "v"(hi));
  return r;
}
// a.hi32lanes <-> b.lo32lanes :  a' = [a.q0,a.q1,b.q0,b.q1], b' = [a.q2,a.q3,b.q2,b.q3]
DEV void pswap32(unsigned& a, unsigned& b) {
  asm("v_permlane32_swap_b32 %0, %1" : "+v"(a), "+v"(b));
}
// odd 16-rows of a <-> even 16-rows of b : a' = [a.r0,b.r0,a.r2,b.r2], b' = [a.r1,b.r1,a.r3,b.r3]
DEV void pswap16(unsigned& a, unsigned& b) {
  asm("v_permlane16_swap_b32 %0, %1" : "+v"(a), "+v"(b));
}

// per-block reduce helper: 256 threads -> (S1,S2) in thread 0
DEV void block_reduce2(float& s, float& s2, float* rs, float* rs2) {
  for (int off = 32; off; off >>= 1) {
    s += __shfl_down(s, off, 64);
    s2 += __shfl_down(s2, off, 64);
  }
  const int wid = threadIdx.x >> 6, lane = threadIdx.x & 63;
  if (lane == 0) { rs[wid] = s; rs2[wid] = s2; }
  __syncthreads();
  if (threadIdx.x == 0) {
    s  = rs[0] + rs[1] + rs[2] + rs[3];
    s2 = rs2[0] + rs2[1] + rs2[2] + rs2[3];
  }
}

// ---------------- all weight transposes in ONE launch (range-decoded) ----------------
__global__ __launch_bounds__(256) void wtr_all_kernel(
    const float* __restrict__ w1, const float* __restrict__ w2,
    const float* __restrict__ a0, const float* __restrict__ a1,
    const float* __restrict__ a2, const float* __restrict__ a3,
    unsigned short* __restrict__ wt1, unsigned short* __restrict__ wt2,
    unsigned short* __restrict__ wtbr) {
  const int blk = blockIdx.x;  // 5248 total
  const float* src; unsigned short* dst; int Cin, Cout, T, base;
  if (blk < 1152)      { src = w1; dst = wt1; Cout = 256; Cin = 128; T = 9; base = 0; }
  else if (blk < 3456) { src = w2; dst = wt2; Cout = 256; Cin = 256; T = 9; base = 1152; }
  else if (blk < 3520) { src = a0; dst = wtbr + (size_t)4 * 64 * 256;
                         Cout = 64; Cin = 256; T = 1; base = 3456; }
  else if (blk < 4096) { src = a1; dst = wtbr + (size_t)1 * 9 * 64 * 256;
                         Cout = 64; Cin = 256; T = 9; base = 3520; }
  else if (blk < 4672) { src = a2; dst = wtbr + (size_t)2 * 9 * 64 * 256;
                         Cout = 64; Cin = 256; T = 9; base = 4096; }
  else                 { src = a3; dst = wtbr + (size_t)3 * 9 * 64 * 256;
                         Cout = 64; Cin = 256; T = 9; base = 4672; }
  int i = (blk - base) * 256 + threadIdx.x;
  int ci = i % Cin;
  int r  = i / Cin;
  int t  = r / Cout;
  int co = r - t * Cout;
  dst[i] = bfc(src[((size_t)co * Cin + ci) * T + t]);
}

// ---------------- maxpool 2x2 -> NHWC bf16 padded (halo=1) ----------------
__global__ __launch_bounds__(256) void pool_kernel(const float* __restrict__ x,
                                                   unsigned short* __restrict__ Pp1) {
  int i = blockIdx.x * 256 + threadIdx.x;  // 524288
  int xg = i & 15, y = (i >> 4) & 63, c = (i >> 10) & 127, b = i >> 17;
  const float* s = x + (((size_t)(b * 128 + c) * 128) + 2 * y) * 128 + 8 * xg;
  float4 u0 = *(const float4*)(s), u1 = *(const float4*)(s + 4);
  float4 u2 = *(const float4*)(s + 128), u3 = *(const float4*)(s + 132);
  float m0 = fmaxf(fmaxf(u0.x, u0.y), fmaxf(u2.x, u2.y));
  float m1 = fmaxf(fmaxf(u0.z, u0.w), fmaxf(u2.z, u2.w));
  float m2 = fmaxf(fmaxf(u1.x, u1.y), fmaxf(u3.x, u3.y));
  float m3 = fmaxf(fmaxf(u1.z, u1.w), fmaxf(u3.z, u3.w));
  unsigned short* d = Pp1 + (((size_t)b * 66 + y + 1) * 66 + xg * 4 + 1) * 128 + c;
  d[0] = bfc(m0); d[128] = bfc(m1); d[256] = bfc(m2); d[384] = bfc(m3);
}

// ---------------- dc conv: implicit GEMM, ci-split x2 (r7 config — measured best) ---
// FROZEN: r8 (co-split) and r9 (co-64 8-wave) both regressed 40-50 us.
template <int CTOT>
__global__ __launch_bounds__(256) void dcconv_kernel(
    const unsigned short* __restrict__ in, const unsigned short* __restrict__ wt,
    float* __restrict__ out) {
  const int Wp = 66, CSEG = CTOT / 2;
  const int w = threadIdx.x >> 6, lane = threadIdx.x & 63;
  const int ln = lane & 15, quad = lane >> 4;
  const int b = blockIdx.z >> 1, h = blockIdx.z & 1, co0 = blockIdx.y * 64;
  const int n0 = blockIdx.x * 128 + w * 32;
  const unsigned short* inb = in + (size_t)b * Wp * Wp * CTOT + h * CSEG;
  const unsigned short* wth = wt + h * CSEG;
  float* outh = out + (size_t)h * 4 * 256 * N;
  size_t pix[2];
#pragma unroll
  for (int j = 0; j < 2; j++) {
    int n = n0 + j * 16 + ln;
    int y = n >> 6, x = n & 63;
    pix[j] = ((size_t)y * Wp + x) * CTOT;
  }
  f32x4 acc[4][2];
#pragma unroll
  for (int i = 0; i < 4; i++)
#pragma unroll
    for (int j = 0; j < 2; j++) acc[i][j] = (f32x4)(0.f);
#pragma unroll
  for (int ky = 0; ky < 3; ky++)
#pragma unroll
    for (int kx = 0; kx < 3; kx++) {
      const size_t toff = ((size_t)ky * Wp + kx) * CTOT;
      const unsigned short* wtap = wth + (size_t)(ky * 3 + kx) * 256 * CTOT;
      for (int kc = 0; kc < CSEG / 32; kc++) {
        const int ko = kc * 32 + quad * 8;
        bf16x8 a[4], bb[2];
#pragma unroll
        for (int i = 0; i < 4; i++)
          a[i] = *(const bf16x8*)(wtap + (size_t)(co0 + i * 16 + ln) * CTOT + ko);
#pragma unroll
        for (int j = 0; j < 2; j++)
          bb[j] = *(const bf16x8*)(inb + pix[j] + toff + ko);
#pragma unroll
        for (int i = 0; i < 4; i++)
#pragma unroll
          for (int j = 0; j < 2; j++)
            acc[i][j] = __builtin_amdgcn_mfma_f32_16x16x32_bf16(a[i], bb[j], acc[i][j], 0, 0, 0);
      }
    }
#pragma unroll
  for (int i = 0; i < 4; i++)
#pragma unroll
    for (int j = 0; j < 2; j++)
#pragma unroll
      for (int r = 0; r < 4; r++)
        outh[((size_t)(b * 256 + co0 + i * 16 + quad * 4 + r)) * N + n0 + j * 16 + ln] =
            acc[i][j][r];
}

// ---------------- all 4 ASPP branches, implicit GEMM on Pp3 (halo=9) ----------------
__global__ __launch_bounds__(256) void branch_kernel(
    const unsigned short* __restrict__ in, const unsigned short* __restrict__ wtall,
    float* __restrict__ br) {
  const int Wp = 82, halo = 9, CIN = 256;
  const int w = threadIdx.x >> 6, lane = threadIdx.x & 63;
  const int ln = lane & 15, quad = lane >> 4;
  const int bb = blockIdx.y;
  const int kbr = bb >> 2, b = bb & 3;
  const int dil = (kbr == 0) ? 1 : 3 * kbr;
  const int klo = (kbr == 0) ? 1 : 0, khi = (kbr == 0) ? 2 : 3;
  const int hd = halo - dil;
  const int cw = (w & 1) * 32, nw = (w >> 1) * 32;
  const int n0 = blockIdx.x * 64 + nw;
  const unsigned short* inb = in + (size_t)b * Wp * Wp * CIN;
  size_t pix[2];
#pragma unroll
  for (int j = 0; j < 2; j++) {
    int n = n0 + j * 16 + ln;
    int y = n >> 6, x = n & 63;
    pix[j] = ((size_t)(y + hd) * Wp + x + hd) * CIN;
  }
  f32x4 acc[2][2];
#pragma unroll
  for (int i = 0; i < 2; i++)
#pragma unroll
    for (int j = 0; j < 2; j++) acc[i][j] = (f32x4)(0.f);
  for (int ky = klo; ky < khi; ky++)
    for (int kx = klo; kx < khi; kx++) {
      const size_t toff = ((size_t)ky * Wp + kx) * dil * CIN;
      const unsigned short* wtap =
          wtall + ((size_t)kbr * 9 + ky * 3 + kx) * 64 * CIN;
      for (int kc = 0; kc < CIN / 32; kc++) {
        const int ko = kc * 32 + quad * 8;
        bf16x8 a[2], bv[2];
#pragma unroll
        for (int i = 0; i < 2; i++)
          a[i] = *(const bf16x8*)(wtap + (size_t)(cw + i * 16 + ln) * CIN + ko);
#pragma unroll
        for (int j = 0; j < 2; j++)
          bv[j] = *(const bf16x8*)(inb + pix[j] + toff + ko);
#pragma unroll
        for (int i = 0; i < 2; i++)
#pragma unroll
          for (int j = 0; j < 2; j++)
            acc[i][j] = __builtin_amdgcn_mfma_f32_16x16x32_bf16(a[i], bv[j], acc[i][j], 0, 0, 0);
      }
    }
#pragma unroll
  for (int i = 0; i < 2; i++)
#pragma unroll
    for (int j = 0; j < 2; j++)
#pragma unroll
      for (int r = 0; r < 4; r++)
        br[((size_t)bb * 64 + cw + i * 16 + quad * 4 + r) * N + n0 + j * 16 + ln] =
            acc[i][j][r];
}

// ---------------- BN partial stats, dc conv (sum of two ci-partials) ----------------
// grid 1024 = 4 b x 256 c (4 blocks/CU, 4x the BW parallelism of the old 256-block
// version). Finalize (sum of 4 b-partials + mean/var) is inlined in the consumer.
__global__ __launch_bounds__(256) void bn_stats2_part_kernel(
    const float* __restrict__ ta, const float* __restrict__ tb,
    float* __restrict__ part) {
  const int c = blockIdx.x & 255, b = blockIdx.x >> 8;
  const size_t base = ((size_t)(b * 256 + c)) * N;
  float s = 0.f, s2 = 0.f;
  for (int i = threadIdx.x; i < N / 4; i += 256) {
    float4 va = *(const float4*)(ta + base + (size_t)i * 4);
    float4 vb = *(const float4*)(tb + base + (size_t)i * 4);
    float v0 = va.x + vb.x, v1 = va.y + vb.y;
    float v2 = va.z + vb.z, v3 = va.w + vb.w;
    s += (v0 + v1) + (v2 + v3);
    s2 = fmaf(v0, v0, s2); s2 = fmaf(v1, v1, s2);
    s2 = fmaf(v2, v2, s2); s2 = fmaf(v3, v3, s2);
  }
  __shared__ float rs[4], rs2[4];
  block_reduce2(s, s2, rs, rs2);
  if (threadIdx.x == 0) {
    part[(size_t)(b * 256 + c) * 2 + 0] = s;
    part[(size_t)(b * 256 + c) * 2 + 1] = s2;
  }
}

// ---------------- BN partial stats, ASPP branch outputs ----------------
// grid 1024 = 4 kbr x 4 b x 64 c; finalize inlined in qkv.
__global__ __launch_bounds__(256) void bn_stats_br_part_kernel(
    const float* __restrict__ br, float* __restrict__ part) {
  const int kbr = blockIdx.x >> 8, rest = blockIdx.x & 255;
  const int b = rest >> 6, c = rest & 63;
  const float* p = br + (size_t)kbr * 1048576 + ((size_t)(b * 64 + c)) * N;
  float s = 0.f, s2 = 0.f;
  for (int i = threadIdx.x; i < N / 4; i += 256) {
    float4 v = *(const float4*)(p + (size_t)i * 4);
    s += (v.x + v.y) + (v.z + v.w);
    s2 = fmaf(v.x, v.x, s2); s2 = fmaf(v.y, v.y, s2);
    s2 = fmaf(v.z, v.z, s2); s2 = fmaf(v.w, v.w, s2);
  }
  __shared__ float rs[4], rs2[4];
  block_reduce2(s, s2, rs, rs2);
  if (threadIdx.x == 0) {
    part[(size_t)((kbr * 4 + b) * 64 + c) * 2 + 0] = s;
    part[(size_t)((kbr * 4 + b) * 64 + c) * 2 + 1] = s2;
  }
}

// ---------------- BN+ReLU (sum of two partials) -> NHWC bf16 padded ----------------
// Finalize of the b-split partials is inlined (cg is block-uniform: 4 threads
// compute sc/of for the block's 4 channels into LDS).
__global__ __launch_bounds__(256) void bn_norm_pad2_kernel(
    const float* __restrict__ ta, const float* __restrict__ tb,
    const float* __restrict__ part, const float* __restrict__ gamma,
    const float* __restrict__ beta, unsigned short* __restrict__ outp,
    int Wp, int halo) {
  __shared__ float ssl[8];
  const int i0g = blockIdx.x * 256;
  const int cgu = (i0g >> 12) & 63;     // block-uniform channel group
  const int c0 = cgu * 4;
  if (threadIdx.x < 4) {
    const int c = c0 + threadIdx.x;
    float S1 = 0.f, S2 = 0.f;
    for (int b = 0; b < Bn; b++) {
      S1 += part[(size_t)(b * 256 + c) * 2 + 0];
      S2 += part[(size_t)(b * 256 + c) * 2 + 1];
    }
    const float cnt = (float)(Bn * N);
    float mean = S1 / cnt;
    float var = S2 / cnt - mean * mean;
    float sc = gamma[c] * rsqrtf(var + 1e-5f);
    ssl[2 * threadIdx.x] = sc;
    ssl[2 * threadIdx.x + 1] = beta[c] - mean * sc;
  }
  __syncthreads();
  int i = i0g + threadIdx.x;
  int n = i & 4095, b = i >> 18;
  ushort4 pk;
  float v0, v1, v2, v3;
  {
    size_t i0 = ((size_t)(b * 256 + c0 + 0)) * N + n;
    size_t i1 = i0 + N, i2 = i1 + N, i3 = i2 + N;
    v0 = fmaxf(fmaf(ta[i0] + tb[i0], ssl[0], ssl[1]), 0.f);
    v1 = fmaxf(fmaf(ta[i1] + tb[i1], ssl[2], ssl[3]), 0.f);
    v2 = fmaxf(fmaf(ta[i2] + tb[i2], ssl[4], ssl[5]), 0.f);
    v3 = fmaxf(fmaf(ta[i3] + tb[i3], ssl[6], ssl[7]), 0.f);
  }
  pk.x = bfc(v0); pk.y = bfc(v1); pk.z = bfc(v2); pk.w = bfc(v3);
  int y = n >> 6, x = n & 63;
  *(ushort4*)(outp + (((size_t)b * Wp + y + halo) * Wp + x + halo) * 256 + c0) = pk;
}

// ---------------- q/k/v 1x1 convs FUSED; branch-BN finalize inlined -----------------
__global__ __launch_bounds__(256) void qkv_kernel(
    const float* __restrict__ br, const float* __restrict__ part,
    const float* __restrict__ g0, const float* __restrict__ b0,
    const float* __restrict__ g1, const float* __restrict__ b1,
    const float* __restrict__ g2, const float* __restrict__ b2,
    const float* __restrict__ g3, const float* __restrict__ b3,
    const float* __restrict__ wq, const float* __restrict__ bq,
    const float* __restrict__ wk, const float* __restrict__ bk,
    const float* __restrict__ wv, const float* __restrict__ bvb,
    unsigned short* __restrict__ qTo, unsigned short* __restrict__ kTo,
    unsigned short* __restrict__ vbo) {
  const int bb = blockIdx.z, dg = blockIdx.y;
  const int kbr = bb >> 2;
  const float* gamma = kbr == 0 ? g0 : (kbr == 1 ? g1 : (kbr == 2 ? g2 : g3));
  const float* beta  = kbr == 0 ? b0 : (kbr == 1 ? b1 : (kbr == 2 ? b2 : b3));
  __shared__ float wl[3][64 * 16];
  __shared__ float ssl[128];
  const int d0b = dg * 16;
  if (threadIdx.x < 64) {
    const int c = threadIdx.x;
    float S1 = 0.f, S2 = 0.f;
    for (int b = 0; b < Bn; b++) {
      const size_t p = (size_t)((kbr * 4 + b) * 64 + c) * 2;
      S1 += part[p]; S2 += part[p + 1];
    }
    const float cnt = (float)(Bn * N);
    float mean = S1 / cnt;
    float var = S2 / cnt - mean * mean;
    float sc = gamma[c] * rsqrtf(var + 1e-5f);
    ssl[2 * c] = sc;
    ssl[2 * c + 1] = beta[c] - mean * sc;
  }
  for (int i = threadIdx.x; i < 64 * 16; i += 256) {
    const size_t widx = (size_t)(d0b + (i & 15)) * 64 + (i >> 4);
    wl[0][i] = wq[widx];
    wl[1][i] = wk[widx];
    wl[2][i] = wv[widx];
  }
  __syncthreads();
  const int tn = threadIdx.x & 63, td = threadIdx.x >> 6;
  const int n0 = blockIdx.x * 256 + tn * 4;
  const int d0 = d0b + td * 4;
  const float* inb = br + (size_t)bb * 64 * N;
  float4 acc[3][4];
#pragma unroll
  for (int j = 0; j < 4; j++) {
    float bq_ = bq[d0 + j], bk_ = bk[d0 + j], bv_ = bvb[d0 + j];
    acc[0][j] = make_float4(bq_, bq_, bq_, bq_);
    acc[1][j] = make_float4(bk_, bk_, bk_, bk_);
    acc[2][j] = make_float4(bv_, bv_, bv_, bv_);
  }
  for (int ci = 0; ci < 64; ci++) {
    float4 u = *(const float4*)(inb + (size_t)ci * N + n0);
    const float sc = ssl[2 * ci], of = ssl[2 * ci + 1];
    u.x = fmaxf(fmaf(u.x, sc, of), 0.f);
    u.y = fmaxf(fmaf(u.y, sc, of), 0.f);
    u.z = fmaxf(fmaf(u.z, sc, of), 0.f);
    u.w = fmaxf(fmaf(u.w, sc, of), 0.f);
#pragma unroll
    for (int p = 0; p < 3; p++) {
      float4 wv4 = *(const float4*)(&wl[p][ci * 16 + td * 4]);
      fma4(acc[p][0], wv4.x, u); fma4(acc[p][1], wv4.y, u);
      fma4(acc[p][2], wv4.z, u); fma4(acc[p][3], wv4.w, u);
    }
  }
  const size_t slab = (size_t)bb * N * 64;
  // q, k: transposed [n][d] bf16
#pragma unroll
  for (int p = 0; p < 2; p++) {
    unsigned short* o = (p == 0 ? qTo : kTo) + slab;
#pragma unroll
    for (int nn = 0; nn < 4; nn++) {
      ushort4 pk;
      pk.x = bfc(((const float*)&acc[p][0])[nn]);
      pk.y = bfc(((const float*)&acc[p][1])[nn]);
      pk.z = bfc(((const float*)&acc[p][2])[nn]);
      pk.w = bfc(((const float*)&acc[p][3])[nn]);
      *(ushort4*)(o + (size_t)(n0 + nn) * 64 + d0) = pk;
    }
  }
  // v: [d][n] bf16
  {
    unsigned short* o = vbo + slab;
#pragma unroll
    for (int j = 0; j < 4; j++) {
      ushort4 pk;
      pk.x = bfc(acc[2][j].x); pk.y = bfc(acc[2][j].y);
      pk.z = bfc(acc[2][j].z); pk.w = bfc(acc[2][j].w);
      *(ushort4*)(o + (size_t)(d0 + j) * N + n0) = pk;
    }
  }
}

// ---------------- posT[n][d] = rel_w[d][h] + rel_h[d][w], bf16 ----------------
__global__ __launch_bounds__(256) void posT_kernel(
    const float* __restrict__ rel_h, const float* __restrict__ rel_w,
    unsigned short* __restrict__ posT) {
  int i = blockIdx.x * 256 + threadIdx.x;  // 65536
  int n = i >> 4, dq = (i & 15) * 4;
  int h = n >> 6, wc = n & 63;
  ushort4 pk;
  pk.x = bfc(rel_w[(dq + 0) * 64 + h] + rel_h[(dq + 0) * 64 + wc]);
  pk.y = bfc(rel_w[(dq + 1) * 64 + h] + rel_h[(dq + 1) * 64 + wc]);
  pk.z = bfc(rel_w[(dq + 2) * 64 + h] + rel_h[(dq + 2) * 64 + wc]);
  pk.w = bfc(rel_w[(dq + 3) * 64 + h] + rel_h[(dq + 3) * 64 + wc]);
  *(ushort4*)(posT + (size_t)n * 64 + dq) = pk;
}

// ---------------- flash v8: 2 c-splits; XCD-pinned; V hoisted (frozen) ---------------
__global__ __launch_bounds__(256, 3) void flash3_kernel(
    const unsigned short* __restrict__ qT, const unsigned short* __restrict__ kT,
    const unsigned short* __restrict__ posT, const unsigned short* __restrict__ vb,
    float* __restrict__ o_part, float* __restrict__ ml) {
  const int lin = blockIdx.x;
  const int xcd = lin & 7, slot = lin >> 3;
  const int bb = xcd * 2 + (slot & 1);
  const int rest = slot >> 1;
  const int mtile = rest & 31, split = rest >> 5;   // split in {0,1}
  const size_t slab = (size_t)bb * N * 64;
  const unsigned short* qTs = qT + slab;
  const unsigned short* kTs = kT + slab;
  const unsigned short* vbs = vb + slab;
  const int w = threadIdx.x >> 6, lane = threadIdx.x & 63;
  const int ln = lane & 15, quad = lane >> 4;
  const int m0 = mtile * 128 + w * 32;  // wave's 32 m-rows (2 frags)
  __shared__ __align__(16) unsigned short As[2][4][64][32];   // 32 KB

  const unsigned short* ssrc = (w < 2) ? kTs : qTs;
  const int rsub = lane >> 2;
  const int csw  = (lane & 3) ^ ((lane >> 3) & 3);
  const int ksub = (w & 1) * 32 + csw * 8;
  auto stage = [&](int c0, int bufi) {
#pragma unroll
    for (int j = 0; j < 4; j++)
      gload_lds16(ssrc + (size_t)(c0 + j * 16 + rsub) * 64 + ksub,
                  &As[bufi][w][j * 16][0]);
  };

  // m-side B fragments: s<2 -> q rows, s>=2 -> pos rows (loaded once)
  bf16x8 bq[4][2];
#pragma unroll
  for (int s = 0; s < 4; s++) {
    const unsigned short* src = (s < 2) ? qTs : posT;
#pragma unroll
    for (int mf = 0; mf < 2; mf++)
      bq[s][mf] = *(const bf16x8*)(src + (size_t)(m0 + mf * 16 + ln) * 64 +
                                   (s & 1) * 32 + quad * 8);
  }

  float m_run[2] = {-3.0e38f, -3.0e38f}, l_run[2] = {0.f, 0.f};
  f32x4 o_acc[4][2];
#pragma unroll
  for (int dt = 0; dt < 4; dt++)
#pragma unroll
    for (int mf = 0; mf < 2; mf++) o_acc[dt][mf] = (f32x4)(0.f);

  const int qsw = (quad ^ ((ln >> 1) & 3)) * 8;  // swizzled read col (halfs)
  const int cbeg = split * 2048;
  stage(cbeg, 0);
  for (int t = 0; t < 32; t++) {
    const int c0 = cbeg + t * 64;
    const int buf = t & 1;
    __syncthreads();               // staging(t) complete; buf (t+1)&1 free
    if (t < 31) stage(c0 + 64, buf ^ 1);  // overlaps compute below
    // ---- S^T from LDS: st[jt][mf][r] = St[c0+jt*16+quad*4+r][m0+mf*16+ln]
    f32x4 st[4][2];
#pragma unroll
    for (int jt = 0; jt < 4; jt++)
#pragma unroll
      for (int mf = 0; mf < 2; mf++) st[jt][mf] = (f32x4)(0.f);
    __builtin_amdgcn_s_setprio(1);
#pragma unroll
    for (int s = 0; s < 4; s++) {
#pragma unroll
      for (int jt = 0; jt < 4; jt++) {
        bf16x8 a = *(const bf16x8*)(&As[buf][s][jt * 16 + ln][qsw]);
#pragma unroll
        for (int mf = 0; mf < 2; mf++)
          st[jt][mf] = __builtin_amdgcn_mfma_f32_16x16x32_bf16(a, bq[s][mf], st[jt][mf], 0, 0, 0);
      }
    }
    __builtin_amdgcn_s_setprio(0);
    // ---- V loads issued EARLY (independent of softmax; latency hides under it)
    bf16x8 av[2][4];
#pragma unroll
    for (int tt = 0; tt < 2; tt++)
#pragma unroll
      for (int dt = 0; dt < 4; dt++)
        av[tt][dt] = *(const bf16x8*)(vbs + (size_t)(dt * 16 + ln) * N + c0 + tt * 32 + quad * 8);
    // ---- online softmax per mf (row state scalar per lane); P stays in regs
    unsigned P0[2][4], P1[2][4];  // [mf][jt]: packed bf16 pairs (c offsets 0,1 / 2,3)
#pragma unroll
    for (int mf = 0; mf < 2; mf++) {
      float mj[4];
#pragma unroll
      for (int jt = 0; jt < 4; jt++)
        mj[jt] = fmaxf(fmaxf(st[jt][mf][0], st[jt][mf][1]),
                       fmaxf(st[jt][mf][2], st[jt][mf][3]));
      float mx = fmaxf(fmaxf(mj[0], mj[1]), fmaxf(mj[2], mj[3]));
      mx = fmaxf(mx, __shfl_xor(mx, 16, 64));
      mx = fmaxf(mx, __shfl_xor(mx, 32, 64));
      // exact skip: if no lane grew, alpha==1.0 for every lane -> rescale is
      // a bit-exact identity and can be skipped entirely.
      if (!__all(mx <= m_run[mf])) {
        const float m_new = fmaxf(m_run[mf], mx);
        const float alpha = __expf(m_run[mf] - m_new);
        l_run[mf] *= alpha;
#pragma unroll
        for (int dt = 0; dt < 4; dt++)
#pragma unroll
          for (int r = 0; r < 4; r++) o_acc[dt][mf][r] *= alpha;
        m_run[mf] = m_new;
      }
      const float mc = m_run[mf];
      float psum = 0.f;
#pragma unroll
      for (int jt = 0; jt < 4; jt++) {
        float e0 = __expf(st[jt][mf][0] - mc);
        float e1 = __expf(st[jt][mf][1] - mc);
        float e2 = __expf(st[jt][mf][2] - mc);
        float e3 = __expf(st[jt][mf][3] - mc);
        psum += (e0 + e1) + (e2 + e3);
        P0[mf][jt] = cvtpk_bf16(e0, e1);
        P1[mf][jt] = cvtpk_bf16(e2, e3);
      }
      psum += __shfl_xor(psum, 16, 64);
      psum += __shfl_xor(psum, 32, 64);
      l_run[mf] += psum;
    }
    // ---- PV: O[d][m] += V[d][c] * P[c][m]
    __builtin_amdgcn_s_setprio(1);
#pragma unroll
    for (int tt = 0; tt < 2; tt++) {
#pragma unroll
      for (int mf = 0; mf < 2; mf++) {
        unsigned x0 = P0[mf][2 * tt], y0 = P0[mf][2 * tt + 1];
        pswap32(x0, y0); pswap16(x0, y0);   // x0 = word0, y0 = word2
        unsigned x1 = P1[mf][2 * tt], y1 = P1[mf][2 * tt + 1];
        pswap32(x1, y1); pswap16(x1, y1);   // x1 = word1, y1 = word3
        union { unsigned u[4]; bf16x8 v; } bp;
        bp.u[0] = x0; bp.u[1] = x1; bp.u[2] = y0; bp.u[3] = y1;
#pragma unroll
        for (int dt = 0; dt < 4; dt++)
          o_acc[dt][mf] = __builtin_amdgcn_mfma_f32_16x16x32_bf16(av[tt][dt], bp.v, o_acc[dt][mf], 0, 0, 0);
      }
    }
    __builtin_amdgcn_s_setprio(0);
  }
  // ---- epilogue: unnormalized partials
  float* ob = o_part + ((size_t)(split * 16 + bb) * 64) * N;
#pragma unroll
  for (int dt = 0; dt < 4; dt++)
#pragma unroll
    for (int mf = 0; mf < 2; mf++)
#pragma unroll
      for (int r = 0; r < 4; r++) {
        int d = dt * 16 + quad * 4 + r;
        ob[(size_t)d * N + m0 + mf * 16 + ln] = o_acc[dt][mf][r];
      }
  if (quad == 0) {
#pragma unroll
    for (int mf = 0; mf < 2; mf++) {
      int m = m0 + mf * 16 + ln;
      ml[((size_t)(split * 16 + bb) * 2 + 0) * N + m] = m_run[mf];
      ml[((size_t)(split * 16 + bb) * 2 + 1) * N + m] = l_run[mf];
    }
  }
}

// ---------------- combine 2 partials -> d_out (weights computed inline) -------------
__global__ __launch_bounds__(256) void comb_kernel(const float* __restrict__ o_part,
                                                   const float* __restrict__ ml,
                                                   float* __restrict__ out) {
  int i = blockIdx.x * 256 + threadIdx.x;
  int m4 = i & 1023, d = (i >> 10) & 63, bb = i >> 16;
  int kbr = bb >> 2, b = bb & 3;
  float mvv[2][4], lvv[2][4];
#pragma unroll
  for (int s = 0; s < 2; s++) {
    float4 t0 = *(const float4*)(ml + ((size_t)(s * 16 + bb) * 2 + 0) * N + m4 * 4);
    float4 t1 = *(const float4*)(ml + ((size_t)(s * 16 + bb) * 2 + 1) * N + m4 * 4);
    mvv[s][0] = t0.x; mvv[s][1] = t0.y; mvv[s][2] = t0.z; mvv[s][3] = t0.w;
    lvv[s][0] = t1.x; lvv[s][1] = t1.y; lvv[s][2] = t1.z; lvv[s][3] = t1.w;
  }
  float w4[2][4];
#pragma unroll
  for (int mm = 0; mm < 4; mm++) {
    float M = fmaxf(mvv[0][mm], mvv[1][mm]);
    float wsc[2], denom = 0.f;
#pragma unroll
    for (int s = 0; s < 2; s++) {
      wsc[s] = __expf(mvv[s][mm] - M);
      denom = fmaf(wsc[s], lvv[s][mm], denom);
    }
    float inv = 1.0f / denom;
#pragma unroll
    for (int s = 0; s < 2; s++) w4[s][mm] = wsc[s] * inv;
  }
  float4 acc = make_float4(0.f, 0.f, 0.f, 0.f);
#pragma unroll
  for (int s = 0; s < 2; s++) {
    const float4 o = *(const float4*)(o_part + ((size_t)(s * 16 + bb) * 64 + d) * N + m4 * 4);
    acc.x = fmaf(o.x, w4[s][0], acc.x); acc.y = fmaf(o.y, w4[s][1], acc.y);
    acc.z = fmaf(o.z, w4[s][2], acc.z); acc.w = fmaf(o.w, w4[s][3], acc.w);
  }
  *(float4*)(out + ((size_t)(b * 256 + kbr * 64 + d)) * N + m4 * 4) = acc;
}

extern "C" void kernel_launch(void* const* d_in, const int* in_sizes, int n_in,
                              void* d_out, int out_size, void* d_ws, size_t ws_size,
                              hipStream_t stream) {
  const float* x      = (const float*)d_in[0];
  const float* dc_w1  = (const float*)d_in[1];
  const float* dc_g1  = (const float*)d_in[3];
  const float* dc_be1 = (const float*)d_in[4];
  const float* dc_w2  = (const float*)d_in[5];
  const float* dc_g2  = (const float*)d_in[7];
  const float* dc_be2 = (const float*)d_in[8];
  const float* aspp_w[4] = {(const float*)d_in[9],  (const float*)d_in[12],
                            (const float*)d_in[15], (const float*)d_in[18]};
  const float* aspp_g[4] = {(const float*)d_in[10], (const float*)d_in[13],
                            (const float*)d_in[16], (const float*)d_in[19]};
  const float* aspp_b[4] = {(const float*)d_in[11], (const float*)d_in[14],
                            (const float*)d_in[17], (const float*)d_in[20]};
  const float* wq = (const float*)d_in[21];
  const float* bq = (const float*)d_in[22];
  const float* wk = (const float*)d_in[23];
  const float* bk = (const float*)d_in[24];
  const float* wv = (const float*)d_in[25];
  const float* bv = (const float*)d_in[26];
  const float* rel_h = (const float*)d_in[27];
  const float* rel_w = (const float*)d_in[28];
  float* out = (float*)d_out;

  float* ws = (float*)d_ws;
  size_t off = 0;
  auto alloc = [&](size_t nf) { float* p = ws + off; off += nf; return p; };
  unsigned short* Pp1 = (unsigned short*)alloc((size_t)4 * 66 * 66 * 128 / 2 + 64);
  unsigned short* Pp2 = (unsigned short*)alloc((size_t)4 * 66 * 66 * 256 / 2 + 64);
  unsigned short* Pp3 = (unsigned short*)alloc((size_t)4 * 82 * 82 * 256 / 2 + 64);
  const size_t HALF = (size_t)4 * 256 * N;
  float* t1   = alloc(2 * HALF);                   // two ci-split partials (r7)
  float* br   = alloc((size_t)4 * 4 * 64 * N);
  float* st1  = alloc(2048);                       // dc1 partials [4b][256c][2]
  float* st2  = alloc(2048);                       // dc2 partials
  float* stbr = alloc(2048);                       // branch partials [16][64][2]
  unsigned short* qT    = (unsigned short*)alloc((size_t)16 * N * 64 / 2);
  unsigned short* kT    = (unsigned short*)alloc((size_t)16 * N * 64 / 2);
  unsigned short* vb    = (unsigned short*)alloc((size_t)16 * N * 64 / 2);
  unsigned short* posT  = (unsigned short*)alloc((size_t)N * 64 / 2);
  unsigned short* wt1   = (unsigned short*)alloc((size_t)9 * 256 * 128 / 2);
  unsigned short* wt2   = (unsigned short*)alloc((size_t)9 * 256 * 256 / 2);
  unsigned short* wtbr  = (unsigned short*)alloc((size_t)4 * 9 * 64 * 256 / 2);
  float* o_part = alloc((size_t)2 * 16 * 64 * N);  // 33.5 MB (2 splits)
  float* mlb    = alloc((size_t)2 * 16 * 2 * N);

  hipMemsetAsync(Pp1, 0, (size_t)4 * 66 * 66 * 128 * 2, stream);
  hipMemsetAsync(Pp2, 0, (size_t)4 * 66 * 66 * 256 * 2, stream);
  hipMemsetAsync(Pp3, 0, (size_t)4 * 82 * 82 * 256 * 2, stream);

  // weight prep: all transposes in one launch
  wtr_all_kernel<<<5248, 256, 0, stream>>>(dc_w1, dc_w2, aspp_w[0], aspp_w[1],
                                           aspp_w[2], aspp_w[3], wt1, wt2, wtbr);

  pool_kernel<<<2048, 256, 0, stream>>>(x, Pp1);

  dcconv_kernel<128><<<dim3(32, 4, 8), 256, 0, stream>>>(Pp1, wt1, t1);
  bn_stats2_part_kernel<<<1024, 256, 0, stream>>>(t1, t1 + HALF, st1);
  bn_norm_pad2_kernel<<<4096, 256, 0, stream>>>(t1, t1 + HALF, st1, dc_g1, dc_be1,
                                                Pp2, 66, 1);
  dcconv_kernel<256><<<dim3(32, 4, 8), 256, 0, stream>>>(Pp2, wt2, t1);
  bn_stats2_part_kernel<<<1024, 256, 0, stream>>>(t1, t1 + HALF, st2);
  bn_norm_pad2_kernel<<<4096, 256, 0, stream>>>(t1, t1 + HALF, st2, dc_g2, dc_be2,
                                                Pp3, 82, 9);

  branch_kernel<<<dim3(64, 16), 256, 0, stream>>>(Pp3, wtbr, br);
  bn_stats_br_part_kernel<<<1024, 256, 0, stream>>>(br, stbr);

  qkv_kernel<<<dim3(16, 4, 16), 256, 0, stream>>>(
      br, stbr, aspp_g[0], aspp_b[0], aspp_g[1], aspp_b[1],
      aspp_g[2], aspp_b[2], aspp_g[3], aspp_b[3],
      wq, bq, wk, bk, wv, bv, qT, kT, vb);
  posT_kernel<<<256, 256, 0, stream>>>(rel_h, rel_w, posT);

  flash3_kernel<<<dim3(1024), 256, 0, stream>>>(qT, kT, posT, vb, o_part, mlb);
  comb_kernel<<<4096, 256, 0, stream>>>(o_part, mlb, out);
}